// Round 4
// baseline (954.751 us; speedup 1.0000x reference)
//
#include <hip/hip_runtime.h>
#include <hip/hip_bf16.h>

#define S3 32768          // 32^3
#define PADD 34
#define PADS (34*34*34)   // 39304
#define CC 219
#define CF 64
#define CPAD 224          // padded channel count for conv inputs
#define CIN_UP 411
#define CUPAD 416         // padded channel count for upsample input
#define ALPHA 0.1f
#define EPS_IN 1e-5f

typedef __attribute__((ext_vector_type(8))) short short8;   // 8 bf16 (4 VGPRs)
typedef __attribute__((ext_vector_type(4))) float floatx4;  // 4 fp32 acc

__device__ __forceinline__ float lrelu(float v){ return v >= 0.f ? v : ALPHA * v; }
__device__ __forceinline__ unsigned short f2bf(float f){
    unsigned int u = __builtin_bit_cast(unsigned int, f);
    u = (u + 0x7FFFu + ((u >> 16) & 1u)) >> 16;   // RNE
    return (unsigned short)u;
}

// ---------------- zero-pad src to [64][34][34][34] fp32 (for corr) ----------------
__global__ __launch_bounds__(256) void pad_kernel(const float* __restrict__ src,
                                                  float* __restrict__ dst){
    int idx = blockIdx.x * 256 + threadIdx.x;
    if (idx >= CF * PADS) return;
    int c = idx / PADS, r = idx % PADS;
    int z = r / (PADD*PADD); int r2 = r % (PADD*PADD);
    int y = r2 / PADD, x = r2 % PADD;
    float v = 0.f;
    if (z >= 1 && z <= 32 && y >= 1 && y <= 32 && x >= 1 && x <= 32)
        v = src[((c*32 + (z-1))*32 + (y-1))*32 + (x-1)];
    dst[idx] = v;
}

// ---------------- correlation volume -> Xp channels [192..219) bf16 ----------------
__global__ __launch_bounds__(256) void corr_kernel(const float* __restrict__ tgt,
                                                   const float* __restrict__ srcp,
                                                   unsigned short* __restrict__ Xp){
    int p = blockIdx.x * 256 + threadIdx.x;   // 0..32767
    int z = p >> 10, y = (p >> 5) & 31, x = p & 31;
    float acc[27];
    #pragma unroll
    for (int k = 0; k < 27; k++) acc[k] = 0.f;
    int pbase = ((z+1)*PADD + (y+1))*PADD + (x+1);
    for (int c = 0; c < CF; c++){
        float t = tgt[c*S3 + p];
        const float* sp = srcp + c*PADS + pbase;
        #pragma unroll
        for (int dz = 0; dz < 3; dz++)
            #pragma unroll
            for (int dy = 0; dy < 3; dy++)
                #pragma unroll
                for (int dx = 0; dx < 3; dx++){
                    int k = (dz*3 + dy)*3 + dx;
                    acc[k] += t * sp[(dz-1)*(PADD*PADD) + (dy-1)*PADD + (dx-1)];
                }
    }
    unsigned short cv[27];
    #pragma unroll
    for (int k = 0; k < 27; k++) cv[k] = f2bf(acc[k] * (1.f/64.f));
    size_t bi = ((size_t)(z+1)*1156 + (y+1)*34 + (x+1))*CPAD + 192;
    uint4 o0, o1, o2;
    o0.x = cv[0]  | ((unsigned)cv[1]<<16);  o0.y = cv[2]  | ((unsigned)cv[3]<<16);
    o0.z = cv[4]  | ((unsigned)cv[5]<<16);  o0.w = cv[6]  | ((unsigned)cv[7]<<16);
    o1.x = cv[8]  | ((unsigned)cv[9]<<16);  o1.y = cv[10] | ((unsigned)cv[11]<<16);
    o1.z = cv[12] | ((unsigned)cv[13]<<16); o1.w = cv[14] | ((unsigned)cv[15]<<16);
    o2.x = cv[16] | ((unsigned)cv[17]<<16); o2.y = cv[18] | ((unsigned)cv[19]<<16);
    o2.z = cv[20] | ((unsigned)cv[21]<<16); o2.w = cv[22] | ((unsigned)cv[23]<<16);
    *(uint4*)&Xp[bi]      = o0;
    *(uint4*)&Xp[bi + 8]  = o1;
    *(uint4*)&Xp[bi + 16] = o2;
    *(unsigned int*)&Xp[bi + 24] = cv[24] | ((unsigned)cv[25]<<16);
    Xp[bi + 26] = cv[26];
}

// ---------------- instance-norm stats: one block per channel ----------------
__global__ __launch_bounds__(256) void stats_kernel(const float* __restrict__ xin,
                                                    float* __restrict__ stats, int nch){
    int c = blockIdx.x;
    const float* p = xin + (size_t)c * S3;
    float s = 0.f, s2 = 0.f;
    for (int i = threadIdx.x; i < S3; i += 256){
        float v = p[i];
        s += v; s2 += v*v;
    }
    #pragma unroll
    for (int off = 32; off > 0; off >>= 1){
        s  += __shfl_xor(s,  off);
        s2 += __shfl_xor(s2, off);
    }
    __shared__ float ls[4], ls2[4];
    int wid = threadIdx.x >> 6;
    if ((threadIdx.x & 63) == 0){ ls[wid] = s; ls2[wid] = s2; }
    __syncthreads();
    if (threadIdx.x == 0){
        float S = 0.f, S2 = 0.f;
        #pragma unroll
        for (int w = 0; w < 4; w++){ S += ls[w]; S2 += ls2[w]; }
        float m   = S * (1.f/S3);
        float var = S2 * (1.f/S3) - m*m;
        stats[c]       = m;
        stats[nch + c] = rsqrtf(var + EPS_IN);
    }
}

// ---------------- apply instance-norm + leaky (fp32, for final Cn) ----------------
__global__ __launch_bounds__(256) void norm_apply_kernel(const float* __restrict__ xin,
                                                         const float* __restrict__ stats,
                                                         float* __restrict__ xout, int nch){
    int idx = blockIdx.x * 256 + threadIdx.x;       // float4 units
    int n4  = nch * (S3/4);
    if (idx >= n4) return;
    int c = idx >> 13;
    float m = stats[c], r = stats[nch + c];
    float4 v = ((const float4*)xin)[idx];
    v.x = lrelu((v.x - m) * r);
    v.y = lrelu((v.y - m) * r);
    v.z = lrelu((v.z - m) * r);
    v.w = lrelu((v.w - m) * r);
    ((float4*)xout)[idx] = v;
}

// ---------------- pack fp32 [C][32^3] -> channel-last bf16 Xp[34^3][224] ----------------
// optional (norm + leaky). dstbase must be multiple of 8.
__global__ __launch_bounds__(256) void pack_kernel(const float* __restrict__ src,
        const float* __restrict__ mean, const float* __restrict__ rstd,
        unsigned short* __restrict__ Xp, int Csrc, int dstbase, int donorm){
    __shared__ float sT[64*33];
    const int row = blockIdx.x;          // z*32+y
    const int chunk = blockIdx.y;
    const int t = threadIdx.x;
    {
        int c = t >> 2, xq = (t & 3) * 8;
        int csrc = chunk*64 + c;
        float4 v0 = make_float4(0.f,0.f,0.f,0.f), v1 = v0;
        float m = 0.f, r = 1.f;
        if (csrc < Csrc){
            const float4* s4 = (const float4*)&src[(size_t)csrc*S3 + row*32 + xq];
            v0 = s4[0]; v1 = s4[1];
            if (donorm){ m = mean[csrc]; r = rstd[csrc]; }
        }
        if (donorm){
            v0.x = lrelu((v0.x-m)*r); v0.y = lrelu((v0.y-m)*r);
            v0.z = lrelu((v0.z-m)*r); v0.w = lrelu((v0.w-m)*r);
            v1.x = lrelu((v1.x-m)*r); v1.y = lrelu((v1.y-m)*r);
            v1.z = lrelu((v1.z-m)*r); v1.w = lrelu((v1.w-m)*r);
        }
        float* sp = &sT[c*33 + xq];
        sp[0]=v0.x; sp[1]=v0.y; sp[2]=v0.z; sp[3]=v0.w;
        sp[4]=v1.x; sp[5]=v1.y; sp[6]=v1.z; sp[7]=v1.w;
    }
    __syncthreads();
    {
        int x = t >> 3, coff = (t & 7) * 8;
        int dstc = dstbase + chunk*64 + coff;
        if (dstc < CPAD){
            unsigned short u[8];
            #pragma unroll
            for (int j = 0; j < 8; j++) u[j] = f2bf(sT[(coff+j)*33 + x]);
            uint4 o;
            o.x = u[0] | ((unsigned)u[1]<<16);
            o.y = u[2] | ((unsigned)u[3]<<16);
            o.z = u[4] | ((unsigned)u[5]<<16);
            o.w = u[6] | ((unsigned)u[7]<<16);
            int z = row >> 5, y = row & 31;
            size_t pos = (size_t)(z+1)*1156 + (y+1)*34 + (x+1);
            *(uint4*)&Xp[pos*CPAD + dstc] = o;
        }
    }
}

// ---------------- pack fp32 [411][16^3] -> channel-last bf16 Cp[18^3][416] ----------------
__global__ __launch_bounds__(256) void pack16_kernel(const float* __restrict__ src,
        unsigned short* __restrict__ Cp){
    __shared__ float sT[64*17];
    const int row = blockIdx.x;   // z'*16+y'
    const int chunk = blockIdx.y; // 0..6
    const int t = threadIdx.x;
    {
        int c = t >> 2, xq = (t & 3) * 4;
        int csrc = chunk*64 + c;
        float4 v = make_float4(0.f,0.f,0.f,0.f);
        if (csrc < CIN_UP)
            v = *(const float4*)&src[(size_t)csrc*4096 + row*16 + xq];
        float* sp = &sT[c*17 + xq];
        sp[0]=v.x; sp[1]=v.y; sp[2]=v.z; sp[3]=v.w;
    }
    __syncthreads();
    {
        int x = t >> 4, coff = (t & 15) * 4;
        int dstc = chunk*64 + coff;
        if (dstc < CUPAD){
            unsigned short u0 = f2bf(sT[(coff+0)*17 + x]);
            unsigned short u1 = f2bf(sT[(coff+1)*17 + x]);
            unsigned short u2 = f2bf(sT[(coff+2)*17 + x]);
            unsigned short u3 = f2bf(sT[(coff+3)*17 + x]);
            uint2 o; o.x = u0 | ((unsigned)u1<<16); o.y = u2 | ((unsigned)u3<<16);
            int z = row >> 4, y = row & 15;
            size_t pos = (size_t)(z+1)*324 + (y+1)*18 + (x+1);
            *(uint2*)&Cp[pos*CUPAD + dstc] = o;
        }
    }
}

// ---------------- pack conv weights: Wt[tap][cb][co 256][ci 32] bf16 ----------------
// perm: our ci order = [tgt 0..127][Cup 128..191][cost 192..218] -> ref concat order
__global__ __launch_bounds__(256) void wpack_kernel(const float* __restrict__ w,
        unsigned short* __restrict__ Wt, int perm){
    int idx = blockIdx.x*256 + threadIdx.x;   // < 27*7*256*32
    int ciin = idx & 31;
    int co   = (idx >> 5) & 255;
    int rest = idx >> 13;        // tap*7+cb
    int cb = rest % 7, tap = rest / 7;
    int ci = cb*32 + ciin;
    float v = 0.f;
    if (co < CC && ci < CC){
        int ciref = ci;
        if (perm) ciref = ci < 128 ? ci : (ci < 192 ? ci + 27 : ci - 64);
        v = w[((size_t)co*CC + ciref)*27 + tap];
    }
    Wt[idx] = f2bf(v);
}

// ---------------- pack out-conv weights: Wt2[tap][cb][co 16][ci 32] bf16 ----------------
__global__ __launch_bounds__(256) void wpack_out_kernel(const float* __restrict__ w,
        unsigned short* __restrict__ Wt2){
    int idx = blockIdx.x*256 + threadIdx.x;   // < 27*7*16*32 = 96768
    if (idx >= 27*7*16*32) return;
    int ciin = idx & 31;
    int co   = (idx >> 5) & 15;
    int rest = idx >> 9;        // tap*7+cb
    int cb = rest % 7, tap = rest / 7;
    int ci = cb*32 + ciin;
    float v = 0.f;
    if (co < 3 && ci < CC)
        v = w[((size_t)co*CC + ci)*27 + tap];
    Wt2[idx] = f2bf(v);
}

// ---------------- pack upsample weights: Wu[parity 8][tap 8][co 64][ci 416] bf16 ----------------
__global__ __launch_bounds__(256) void wupack_kernel(const float* __restrict__ w,
        unsigned short* __restrict__ Wu){
    int idx = blockIdx.x*256 + threadIdx.x;  // < 8*8*64*416
    int ci = idx % CUPAD;
    int rest = idx / CUPAD;
    int co = rest & 63;
    int pj = rest >> 6;
    int j = pj & 7, p = pj >> 3;
    float v = 0.f;
    if (ci < CIN_UP){
        int oz = p>>2, oy = (p>>1)&1, ox = p&1;
        int jz = j>>2, jy = (j>>1)&1, jx = j&1;
        int wz = 3 - oz - 2*jz, wy = 3 - oy - 2*jy, wx = 3 - ox - 2*jx;
        v = w[(((size_t)ci*64 + co)*64) + wz*16 + wy*4 + wx];
    }
    Wu[idx] = f2bf(v);
}

// ---------------- upsample via MFMA: per-parity GEMM M=64, N=16^3, K=8*416 ----------------
__global__ __launch_bounds__(256,2) void ups_mfma_kernel(const unsigned short* __restrict__ Cp,
        const unsigned short* __restrict__ Wu, float* __restrict__ U){
    __shared__ unsigned short sA[64*40];
    __shared__ unsigned short sB[64*40];
    const int nt = blockIdx.x;          // 512 = parity(8) x z'(16) x ygrp(4)
    const int p  = nt >> 6;
    const int zp = (nt >> 2) & 15;
    const int y0 = (nt & 3) * 4;
    const int oz = p>>2, oy = (p>>1)&1, ox = p&1;
    const int t = threadIdx.x, w = t>>6, l = t&63;
    const int mw = (w&1)*32, nw = (w>>1)*32;
    const int lm = l&15, lq = l>>4;
    const int sn = t>>2, spart = (t&3)*8;
    const int sr = sn>>4, sx = sn&15;
    floatx4 acc[2][2];
    #pragma unroll
    for (int i=0;i<2;i++)
        #pragma unroll
        for (int j=0;j<2;j++) acc[i][j] = (floatx4){0.f,0.f,0.f,0.f};

    for (int j = 0; j < 8; ++j){
        int sz = oz + (j>>2), sy = oy + ((j>>1)&1), sxx = ox + (j&1);
        size_t pbase = ((size_t)(zp+sz)*324 + (y0+sr+sy)*18 + (sx+sxx)) * CUPAD;
        size_t abase = ((size_t)(p*8 + j)*64 + sn)*CUPAD;
        for (int cb = 0; cb < 13; ++cb){
            uint4 av = *(const uint4*)&Wu[abase + cb*32 + spart];
            uint4 bv = *(const uint4*)&Cp[pbase + cb*32 + spart];
            *(uint4*)&sA[sn*40 + spart] = av;
            *(uint4*)&sB[sn*40 + spart] = bv;
            __syncthreads();
            short8 af[2], bfv[2];
            #pragma unroll
            for (int i=0;i<2;i++){
                af[i]  = *(const short8*)&sA[(mw + i*16 + lm)*40 + lq*8];
                bfv[i] = *(const short8*)&sB[(nw + i*16 + lm)*40 + lq*8];
            }
            #pragma unroll
            for (int i=0;i<2;i++)
                #pragma unroll
                for (int jj=0;jj<2;jj++)
                    acc[i][jj] = __builtin_amdgcn_mfma_f32_16x16x32_bf16(af[i], bfv[jj], acc[i][jj], 0,0,0);
            __syncthreads();
        }
    }
    #pragma unroll
    for (int i=0;i<2;i++){
        #pragma unroll
        for (int jj=0;jj<2;jj++){
            int n = nw + jj*16 + lm;
            int yy = y0 + (n>>4), xx = n&15;
            size_t opos = ((size_t)(2*zp+oz)<<10) + ((size_t)(2*yy+oy)<<5) + (2*xx+ox);
            #pragma unroll
            for (int r=0;r<4;r++){
                int co = mw + i*16 + lq*4 + r;
                U[(size_t)co*S3 + opos] = acc[i][jj][r];
            }
        }
    }
}

// ---------------- 3x3x3 conv via MFMA, persistent-B tile ----------------
// Block: M=128 (mt half of co), N=128 (4 y-rows x 32 x), fixed z.
// Per ci-chunk: stage [3z][6y][34x][32ci] once into LDS (pad->40), then 27 taps
// barrier-free; A-fragments prefetched from global (L2-resident Wt).
__global__ __launch_bounds__(256,2) void conv_mfma_kernel(const unsigned short* __restrict__ Xp,
        const unsigned short* __restrict__ Wt, const float* __restrict__ bg,
        float* __restrict__ Y){
    __shared__ unsigned short sB[612*40];   // 48,960 B
    const int nt = blockIdx.x;     // 0..255: z(32) x ygrp(8)
    const int mt = blockIdx.y;     // 0..1
    const int z  = nt >> 3;
    const int y0 = (nt & 7) * 4;
    const int t = threadIdx.x, w = t>>6, l = t&63;
    const int mw = (w & 1) * 64, nw = (w >> 1) * 64;
    const int lm = l & 15, lq = l >> 4;

    floatx4 acc[4][4];
    #pragma unroll
    for (int i=0;i<4;i++)
        #pragma unroll
        for (int j=0;j<4;j++) acc[i][j] = (floatx4){0.f,0.f,0.f,0.f};

    for (int cb = 0; cb < 7; ++cb){
        __syncthreads();
        // stage 612 pixels x 32 ci (4 x b128 each)
        for (int idx = t; idx < 2448; idx += 256){
            int p = idx >> 2, q = idx & 3;
            int zz = p / 204, rem = p % 204;
            int yy = rem / 34, x = rem - yy*34;
            uint4 v = *(const uint4*)&Xp[((size_t)((z+zz)*1156 + (y0+yy)*34 + x))*CPAD + cb*32 + q*8];
            *(uint4*)&sB[p*40 + q*8] = v;
        }
        __syncthreads();
        const unsigned short* wp = Wt + ((size_t)(cb*256 + mt*128 + mw + lm))*32 + lq*8;
        short8 a0 = *(const short8*)(wp);
        short8 a1 = *(const short8*)(wp + 512);
        short8 a2 = *(const short8*)(wp + 1024);
        short8 a3 = *(const short8*)(wp + 1536);
        #pragma unroll 1
        for (int tap = 0; tap < 27; ++tap){
            int tn = tap < 26 ? tap + 1 : tap;
            const unsigned short* wn = wp + (size_t)tn*57344;   // 7*256*32 per tap
            short8 n0 = *(const short8*)(wn);
            short8 n1 = *(const short8*)(wn + 512);
            short8 n2 = *(const short8*)(wn + 1024);
            short8 n3 = *(const short8*)(wn + 1536);
            const int dz = tap/9, dy = (tap/3)%3, dx = tap%3;
            short8 bfv[4];
            #pragma unroll
            for (int j=0;j<4;j++){
                int n = nw + j*16 + lm;
                int r = n >> 5, x = n & 31;
                bfv[j] = *(const short8*)&sB[(dz*204 + (r+dy)*34 + (x+dx))*40 + lq*8];
            }
            short8 af[4] = {a0, a1, a2, a3};
            #pragma unroll
            for (int i=0;i<4;i++)
                #pragma unroll
                for (int j=0;j<4;j++)
                    acc[i][j] = __builtin_amdgcn_mfma_f32_16x16x32_bf16(af[i], bfv[j], acc[i][j], 0,0,0);
            a0 = n0; a1 = n1; a2 = n2; a3 = n3;
        }
    }
    #pragma unroll
    for (int i=0;i<4;i++){
        #pragma unroll
        for (int j=0;j<4;j++){
            const int n = nw + j*16 + lm;
            const size_t pp = ((size_t)z<<10) + ((size_t)(y0 + (n>>5))<<5) + (n&31);
            #pragma unroll
            for (int r=0;r<4;r++){
                int gm = mt*128 + mw + i*16 + lq*4 + r;
                if (gm < CC) Y[(size_t)gm*S3 + pp] = acc[i][j][r] + bg[gm];
            }
        }
    }
}

// ---------------- final 219->3 conv via MFMA, persistent-B tile ----------------
__global__ __launch_bounds__(256,2) void convout_mfma_kernel(const unsigned short* __restrict__ Xp,
        const unsigned short* __restrict__ Wt2, const float* __restrict__ bgl,
        float* __restrict__ Y){
    __shared__ unsigned short sB[612*40];
    const int nt = blockIdx.x;      // z(32) x ygrp(8)
    const int z  = nt >> 3;
    const int y0 = (nt & 7) * 4;
    const int t = threadIdx.x, w = t>>6, l = t&63;
    const int nw = w * 32;
    const int lm = l & 15, lq = l >> 4;
    floatx4 acc[2];
    acc[0] = (floatx4){0.f,0.f,0.f,0.f};
    acc[1] = (floatx4){0.f,0.f,0.f,0.f};

    for (int cb = 0; cb < 7; ++cb){
        __syncthreads();
        for (int idx = t; idx < 2448; idx += 256){
            int p = idx >> 2, q = idx & 3;
            int zz = p / 204, rem = p % 204;
            int yy = rem / 34, x = rem - yy*34;
            uint4 v = *(const uint4*)&Xp[((size_t)((z+zz)*1156 + (y0+yy)*34 + x))*CPAD + cb*32 + q*8];
            *(uint4*)&sB[p*40 + q*8] = v;
        }
        __syncthreads();
        const unsigned short* wp = Wt2 + ((size_t)(cb*16 + lm))*32 + lq*8;
        short8 a0 = *(const short8*)wp;
        #pragma unroll 1
        for (int tap = 0; tap < 27; ++tap){
            int tn = tap < 26 ? tap + 1 : tap;
            short8 an = *(const short8*)(wp + (size_t)tn*3584);   // 7*16*32 per tap
            const int dz = tap/9, dy = (tap/3)%3, dx = tap%3;
            #pragma unroll
            for (int j=0;j<2;j++){
                int n = nw + j*16 + lm;
                int r = n >> 5, x = n & 31;
                short8 bf = *(const short8*)&sB[(dz*204 + (r+dy)*34 + (x+dx))*40 + lq*8];
                acc[j] = __builtin_amdgcn_mfma_f32_16x16x32_bf16(a0, bf, acc[j], 0,0,0);
            }
            a0 = an;
        }
    }
    if (lq == 0){
        #pragma unroll
        for (int j = 0; j < 2; j++){
            int n = nw + j*16 + lm;
            size_t pp = ((size_t)z<<10) + ((size_t)(y0 + (n>>5))<<5) + (n&31);
            #pragma unroll
            for (int r = 0; r < 3; r++)
                Y[(size_t)r*S3 + pp] = acc[j][r] + bgl[r];
        }
    }
}

extern "C" void kernel_launch(void* const* d_in, const int* in_sizes, int n_in,
                              void* d_out, int out_size, void* d_ws, size_t ws_size,
                              hipStream_t stream) {
    const float* src   = (const float*)d_in[0];
    const float* tgt   = (const float*)d_in[1];
    const float* Cmat  = (const float*)d_in[2];
    const float* up_w  = (const float*)d_in[3];
    const float* c1_w  = (const float*)d_in[5];
    const float* c1_b  = (const float*)d_in[6];
    const float* c2_w  = (const float*)d_in[7];
    const float* c2_b  = (const float*)d_in[8];
    const float* out_w = (const float*)d_in[9];
    const float* out_b = (const float*)d_in[10];

    float* out = (float*)d_out;                          // Cn [219*S3] then out [3*S3]
    char* ws = (char*)d_ws;
    unsigned short* Xp = (unsigned short*)ws;            // 34^3 x 224 bf16 = 17,608,192 B
    float*  U  = (float*)(ws + 17608192);                // 64*S3 fp32 = 8,388,608 B
    unsigned short* Wt = (unsigned short*)(ws + 17608192);       // aliases U (3,096,576 B)
    unsigned short* Cp = (unsigned short*)(ws + 25996800);       // 18^3 x 416 bf16 = 4,852,224 B
    unsigned short* Wu = (unsigned short*)(ws + 25996800 + 4852224); // 3,407,872 B
    float* srcp = (float*)(ws + 25996800);               // aliases Cp/Wu (10,061,824 B)
    unsigned short* Wt2 = (unsigned short*)(ws + 25996800); // aliases srcp after corr (193,536 B)
    float* stats = (float*)(ws + 36058624);              // 2 KB

    hipMemsetAsync(Xp, 0, 17608192, stream);             // halo + pad channels
    hipMemsetAsync(Cp, 0, 4852224, stream);

    // ---- upsample (411->64, k4 s2) as 8 parity GEMMs + instance-norm + leaky ----
    pack16_kernel<<<dim3(256,7), 256, 0, stream>>>(Cmat, Cp);
    wupack_kernel<<<6656, 256, 0, stream>>>(up_w, Wu);
    ups_mfma_kernel<<<512, 256, 0, stream>>>(Cp, Wu, U);
    stats_kernel<<<64, 256, 0, stream>>>(U, stats, 64);
    pack_kernel<<<dim3(1024,1), 256, 0, stream>>>(U, stats, stats+64, Xp, 64, 128, 1); // Cup -> ch 128..191
    // ---- concat: tgt -> ch 0..63, src -> ch 64..127 (raw) ----
    pack_kernel<<<dim3(1024,1), 256, 0, stream>>>(tgt, nullptr, nullptr, Xp, 64, 0, 0);
    pack_kernel<<<dim3(1024,1), 256, 0, stream>>>(src, nullptr, nullptr, Xp, 64, 64, 0);
    // ---- correlation volume -> ch 192..218 ----
    pad_kernel<<<9826, 256, 0, stream>>>(src, srcp);
    corr_kernel<<<128, 256, 0, stream>>>(tgt, srcp, Xp);
    // ---- out-conv weight pack (srcp region is free after corr) ----
    wpack_out_kernel<<<378, 256, 0, stream>>>(out_w, Wt2);
    // ---- conv1 (219->219) MFMA ----
    wpack_kernel<<<6048, 256, 0, stream>>>(c1_w, Wt, 1);
    conv_mfma_kernel<<<dim3(256,2), 256, 0, stream>>>(Xp, Wt, c1_b, out);
    stats_kernel<<<219, 256, 0, stream>>>(out, stats, 219);
    pack_kernel<<<dim3(1024,4), 256, 0, stream>>>(out, stats, stats+219, Xp, 219, 0, 1);
    // ---- conv2 (219->219) MFMA ----
    wpack_kernel<<<6048, 256, 0, stream>>>(c2_w, Wt, 0);
    conv_mfma_kernel<<<dim3(256,2), 256, 0, stream>>>(Xp, Wt, c2_b, out);
    // ---- norm + leaky: fp32 Cn to d_out, bf16 packed Cn to Xp ----
    stats_kernel<<<219, 256, 0, stream>>>(out, stats, 219);
    pack_kernel<<<dim3(1024,4), 256, 0, stream>>>(out, stats, stats+219, Xp, 219, 0, 1);
    norm_apply_kernel<<<(219*(S3/4))/256, 256, 0, stream>>>(out, stats, out, 219);
    // ---- final 219->3 conv via MFMA ----
    convout_mfma_kernel<<<256, 256, 0, stream>>>(Xp, Wt2, out_b, out + (size_t)CC*S3);
}

// Round 5
// 808.896 us; speedup vs baseline: 1.1803x; 1.1803x over previous
//
#include <hip/hip_runtime.h>
#include <hip/hip_bf16.h>

#define S3 32768          // 32^3
#define PADD 34
#define PADS (34*34*34)   // 39304
#define CC 219
#define CF 64
#define CPAD 224          // padded channel count for conv inputs
#define CIN_UP 411
#define CUPAD 416         // padded channel count for upsample input
#define ALPHA 0.1f
#define EPS_IN 1e-5f

typedef __attribute__((ext_vector_type(8))) short short8;   // 8 bf16 (4 VGPRs)
typedef __attribute__((ext_vector_type(4))) float floatx4;  // 4 fp32 acc

__device__ __forceinline__ float lrelu(float v){ return v >= 0.f ? v : ALPHA * v; }
__device__ __forceinline__ unsigned short f2bf(float f){
    unsigned int u = __builtin_bit_cast(unsigned int, f);
    u = (u + 0x7FFFu + ((u >> 16) & 1u)) >> 16;   // RNE
    return (unsigned short)u;
}
// async global->LDS DMA, 16B per lane; LDS dest = wave-uniform base + lane*16
__device__ __forceinline__ void gld16(const unsigned short* g, unsigned short* l){
    __builtin_amdgcn_global_load_lds(
        (const __attribute__((address_space(1))) unsigned int*)g,
        (__attribute__((address_space(3))) unsigned int*)l, 16, 0, 0);
}

// ---------------- zero-pad src to [64][34][34][34] fp32 (for corr) ----------------
__global__ __launch_bounds__(256) void pad_kernel(const float* __restrict__ src,
                                                  float* __restrict__ dst){
    int idx = blockIdx.x * 256 + threadIdx.x;
    if (idx >= CF * PADS) return;
    int c = idx / PADS, r = idx % PADS;
    int z = r / (PADD*PADD); int r2 = r % (PADD*PADD);
    int y = r2 / PADD, x = r2 % PADD;
    float v = 0.f;
    if (z >= 1 && z <= 32 && y >= 1 && y <= 32 && x >= 1 && x <= 32)
        v = src[((c*32 + (z-1))*32 + (y-1))*32 + (x-1)];
    dst[idx] = v;
}

// ---------------- correlation volume -> Xp channels [192..219) bf16 ----------------
__global__ __launch_bounds__(256) void corr_kernel(const float* __restrict__ tgt,
                                                   const float* __restrict__ srcp,
                                                   unsigned short* __restrict__ Xp){
    int p = blockIdx.x * 256 + threadIdx.x;   // 0..32767
    int z = p >> 10, y = (p >> 5) & 31, x = p & 31;
    float acc[27];
    #pragma unroll
    for (int k = 0; k < 27; k++) acc[k] = 0.f;
    int pbase = ((z+1)*PADD + (y+1))*PADD + (x+1);
    for (int c = 0; c < CF; c++){
        float t = tgt[c*S3 + p];
        const float* sp = srcp + c*PADS + pbase;
        #pragma unroll
        for (int dz = 0; dz < 3; dz++)
            #pragma unroll
            for (int dy = 0; dy < 3; dy++)
                #pragma unroll
                for (int dx = 0; dx < 3; dx++){
                    int k = (dz*3 + dy)*3 + dx;
                    acc[k] += t * sp[(dz-1)*(PADD*PADD) + (dy-1)*PADD + (dx-1)];
                }
    }
    unsigned short cv[27];
    #pragma unroll
    for (int k = 0; k < 27; k++) cv[k] = f2bf(acc[k] * (1.f/64.f));
    size_t bi = ((size_t)(z+1)*1156 + (y+1)*34 + (x+1))*CPAD + 192;
    uint4 o0, o1, o2;
    o0.x = cv[0]  | ((unsigned)cv[1]<<16);  o0.y = cv[2]  | ((unsigned)cv[3]<<16);
    o0.z = cv[4]  | ((unsigned)cv[5]<<16);  o0.w = cv[6]  | ((unsigned)cv[7]<<16);
    o1.x = cv[8]  | ((unsigned)cv[9]<<16);  o1.y = cv[10] | ((unsigned)cv[11]<<16);
    o1.z = cv[12] | ((unsigned)cv[13]<<16); o1.w = cv[14] | ((unsigned)cv[15]<<16);
    o2.x = cv[16] | ((unsigned)cv[17]<<16); o2.y = cv[18] | ((unsigned)cv[19]<<16);
    o2.z = cv[20] | ((unsigned)cv[21]<<16); o2.w = cv[22] | ((unsigned)cv[23]<<16);
    *(uint4*)&Xp[bi]      = o0;
    *(uint4*)&Xp[bi + 8]  = o1;
    *(uint4*)&Xp[bi + 16] = o2;
    *(unsigned int*)&Xp[bi + 24] = cv[24] | ((unsigned)cv[25]<<16);
    Xp[bi + 26] = cv[26];
}

// ---------------- instance-norm stats: one block per channel ----------------
__global__ __launch_bounds__(256) void stats_kernel(const float* __restrict__ xin,
                                                    float* __restrict__ stats, int nch){
    int c = blockIdx.x;
    const float* p = xin + (size_t)c * S3;
    float s = 0.f, s2 = 0.f;
    for (int i = threadIdx.x; i < S3; i += 256){
        float v = p[i];
        s += v; s2 += v*v;
    }
    #pragma unroll
    for (int off = 32; off > 0; off >>= 1){
        s  += __shfl_xor(s,  off);
        s2 += __shfl_xor(s2, off);
    }
    __shared__ float ls[4], ls2[4];
    int wid = threadIdx.x >> 6;
    if ((threadIdx.x & 63) == 0){ ls[wid] = s; ls2[wid] = s2; }
    __syncthreads();
    if (threadIdx.x == 0){
        float S = 0.f, S2 = 0.f;
        #pragma unroll
        for (int w = 0; w < 4; w++){ S += ls[w]; S2 += ls2[w]; }
        float m   = S * (1.f/S3);
        float var = S2 * (1.f/S3) - m*m;
        stats[c]       = m;
        stats[nch + c] = rsqrtf(var + EPS_IN);
    }
}

// ---------------- apply instance-norm + leaky (fp32, for final Cn) ----------------
__global__ __launch_bounds__(256) void norm_apply_kernel(const float* __restrict__ xin,
                                                         const float* __restrict__ stats,
                                                         float* __restrict__ xout, int nch){
    int idx = blockIdx.x * 256 + threadIdx.x;       // float4 units
    int n4  = nch * (S3/4);
    if (idx >= n4) return;
    int c = idx >> 13;
    float m = stats[c], r = stats[nch + c];
    float4 v = ((const float4*)xin)[idx];
    v.x = lrelu((v.x - m) * r);
    v.y = lrelu((v.y - m) * r);
    v.z = lrelu((v.z - m) * r);
    v.w = lrelu((v.w - m) * r);
    ((float4*)xout)[idx] = v;
}

// ---------------- pack fp32 [C][32^3] -> channel-last bf16 Xp[34^3][224] ----------------
// optional (norm + leaky). dstbase must be multiple of 8.
__global__ __launch_bounds__(256) void pack_kernel(const float* __restrict__ src,
        const float* __restrict__ mean, const float* __restrict__ rstd,
        unsigned short* __restrict__ Xp, int Csrc, int dstbase, int donorm){
    __shared__ float sT[64*33];
    const int row = blockIdx.x;          // z*32+y
    const int chunk = blockIdx.y;
    const int t = threadIdx.x;
    {
        int c = t >> 2, xq = (t & 3) * 8;
        int csrc = chunk*64 + c;
        float4 v0 = make_float4(0.f,0.f,0.f,0.f), v1 = v0;
        float m = 0.f, r = 1.f;
        if (csrc < Csrc){
            const float4* s4 = (const float4*)&src[(size_t)csrc*S3 + row*32 + xq];
            v0 = s4[0]; v1 = s4[1];
            if (donorm){ m = mean[csrc]; r = rstd[csrc]; }
        }
        if (donorm){
            v0.x = lrelu((v0.x-m)*r); v0.y = lrelu((v0.y-m)*r);
            v0.z = lrelu((v0.z-m)*r); v0.w = lrelu((v0.w-m)*r);
            v1.x = lrelu((v1.x-m)*r); v1.y = lrelu((v1.y-m)*r);
            v1.z = lrelu((v1.z-m)*r); v1.w = lrelu((v1.w-m)*r);
        }
        float* sp = &sT[c*33 + xq];
        sp[0]=v0.x; sp[1]=v0.y; sp[2]=v0.z; sp[3]=v0.w;
        sp[4]=v1.x; sp[5]=v1.y; sp[6]=v1.z; sp[7]=v1.w;
    }
    __syncthreads();
    {
        int x = t >> 3, coff = (t & 7) * 8;
        int dstc = dstbase + chunk*64 + coff;
        if (dstc < CPAD){
            unsigned short u[8];
            #pragma unroll
            for (int j = 0; j < 8; j++) u[j] = f2bf(sT[(coff+j)*33 + x]);
            uint4 o;
            o.x = u[0] | ((unsigned)u[1]<<16);
            o.y = u[2] | ((unsigned)u[3]<<16);
            o.z = u[4] | ((unsigned)u[5]<<16);
            o.w = u[6] | ((unsigned)u[7]<<16);
            int z = row >> 5, y = row & 31;
            size_t pos = (size_t)(z+1)*1156 + (y+1)*34 + (x+1);
            *(uint4*)&Xp[pos*CPAD + dstc] = o;
        }
    }
}

// ---------------- pack fp32 [411][16^3] -> channel-last bf16 Cp[18^3][416] ----------------
__global__ __launch_bounds__(256) void pack16_kernel(const float* __restrict__ src,
        unsigned short* __restrict__ Cp){
    __shared__ float sT[64*17];
    const int row = blockIdx.x;   // z'*16+y'
    const int chunk = blockIdx.y; // 0..6
    const int t = threadIdx.x;
    {
        int c = t >> 2, xq = (t & 3) * 4;
        int csrc = chunk*64 + c;
        float4 v = make_float4(0.f,0.f,0.f,0.f);
        if (csrc < CIN_UP)
            v = *(const float4*)&src[(size_t)csrc*4096 + row*16 + xq];
        float* sp = &sT[c*17 + xq];
        sp[0]=v.x; sp[1]=v.y; sp[2]=v.z; sp[3]=v.w;
    }
    __syncthreads();
    {
        int x = t >> 4, coff = (t & 15) * 4;
        int dstc = chunk*64 + coff;
        if (dstc < CUPAD){
            unsigned short u0 = f2bf(sT[(coff+0)*17 + x]);
            unsigned short u1 = f2bf(sT[(coff+1)*17 + x]);
            unsigned short u2 = f2bf(sT[(coff+2)*17 + x]);
            unsigned short u3 = f2bf(sT[(coff+3)*17 + x]);
            uint2 o; o.x = u0 | ((unsigned)u1<<16); o.y = u2 | ((unsigned)u3<<16);
            int z = row >> 4, y = row & 15;
            size_t pos = (size_t)(z+1)*324 + (y+1)*18 + (x+1);
            *(uint2*)&Cp[pos*CUPAD + dstc] = o;
        }
    }
}

// ---------------- pack conv weights: Wt[tap][cb][co 256][ci 32] bf16 ----------------
// perm: our ci order = [tgt 0..127][Cup 128..191][cost 192..218] -> ref concat order
__global__ __launch_bounds__(256) void wpack_kernel(const float* __restrict__ w,
        unsigned short* __restrict__ Wt, int perm){
    int idx = blockIdx.x*256 + threadIdx.x;   // < 27*7*256*32
    int ciin = idx & 31;
    int co   = (idx >> 5) & 255;
    int rest = idx >> 13;        // tap*7+cb
    int cb = rest % 7, tap = rest / 7;
    int ci = cb*32 + ciin;
    float v = 0.f;
    if (co < CC && ci < CC){
        int ciref = ci;
        if (perm) ciref = ci < 128 ? ci : (ci < 192 ? ci + 27 : ci - 64);
        v = w[((size_t)co*CC + ciref)*27 + tap];
    }
    Wt[idx] = f2bf(v);
}

// ---------------- pack out-conv weights: Wt2[tap][cb][co 16][ci 32] bf16 ----------------
__global__ __launch_bounds__(256) void wpack_out_kernel(const float* __restrict__ w,
        unsigned short* __restrict__ Wt2){
    int idx = blockIdx.x*256 + threadIdx.x;   // < 27*7*16*32 = 96768
    if (idx >= 27*7*16*32) return;
    int ciin = idx & 31;
    int co   = (idx >> 5) & 15;
    int rest = idx >> 9;        // tap*7+cb
    int cb = rest % 7, tap = rest / 7;
    int ci = cb*32 + ciin;
    float v = 0.f;
    if (co < 3 && ci < CC)
        v = w[((size_t)co*CC + ci)*27 + tap];
    Wt2[idx] = f2bf(v);
}

// ---------------- pack upsample weights: Wu[parity 8][tap 8][co 64][ci 416] bf16 ----------------
__global__ __launch_bounds__(256) void wupack_kernel(const float* __restrict__ w,
        unsigned short* __restrict__ Wu){
    int idx = blockIdx.x*256 + threadIdx.x;  // < 8*8*64*416
    int ci = idx % CUPAD;
    int rest = idx / CUPAD;
    int co = rest & 63;
    int pj = rest >> 6;
    int j = pj & 7, p = pj >> 3;
    float v = 0.f;
    if (ci < CIN_UP){
        int oz = p>>2, oy = (p>>1)&1, ox = p&1;
        int jz = j>>2, jy = (j>>1)&1, jx = j&1;
        int wz = 3 - oz - 2*jz, wy = 3 - oy - 2*jy, wx = 3 - ox - 2*jx;
        v = w[(((size_t)ci*64 + co)*64) + wz*16 + wy*4 + wx];
    }
    Wu[idx] = f2bf(v);
}

// ---------------- upsample via MFMA: per-parity GEMM M=64, N=16^3, K=8*416 ----------------
__global__ __launch_bounds__(256,2) void ups_mfma_kernel(const unsigned short* __restrict__ Cp,
        const unsigned short* __restrict__ Wu, float* __restrict__ U){
    __shared__ unsigned short sA[64*40];
    __shared__ unsigned short sB[64*40];
    const int nt = blockIdx.x;          // 512 = parity(8) x z'(16) x ygrp(4)
    const int p  = nt >> 6;
    const int zp = (nt >> 2) & 15;
    const int y0 = (nt & 3) * 4;
    const int oz = p>>2, oy = (p>>1)&1, ox = p&1;
    const int t = threadIdx.x, w = t>>6, l = t&63;
    const int mw = (w&1)*32, nw = (w>>1)*32;
    const int lm = l&15, lq = l>>4;
    const int sn = t>>2, spart = (t&3)*8;
    const int sr = sn>>4, sx = sn&15;
    floatx4 acc[2][2];
    #pragma unroll
    for (int i=0;i<2;i++)
        #pragma unroll
        for (int j=0;j<2;j++) acc[i][j] = (floatx4){0.f,0.f,0.f,0.f};

    for (int j = 0; j < 8; ++j){
        int sz = oz + (j>>2), sy = oy + ((j>>1)&1), sxx = ox + (j&1);
        size_t pbase = ((size_t)(zp+sz)*324 + (y0+sr+sy)*18 + (sx+sxx)) * CUPAD;
        size_t abase = ((size_t)(p*8 + j)*64 + sn)*CUPAD;
        for (int cb = 0; cb < 13; ++cb){
            uint4 av = *(const uint4*)&Wu[abase + cb*32 + spart];
            uint4 bv = *(const uint4*)&Cp[pbase + cb*32 + spart];
            *(uint4*)&sA[sn*40 + spart] = av;
            *(uint4*)&sB[sn*40 + spart] = bv;
            __syncthreads();
            short8 af[2], bfv[2];
            #pragma unroll
            for (int i=0;i<2;i++){
                af[i]  = *(const short8*)&sA[(mw + i*16 + lm)*40 + lq*8];
                bfv[i] = *(const short8*)&sB[(nw + i*16 + lm)*40 + lq*8];
            }
            #pragma unroll
            for (int i=0;i<2;i++)
                #pragma unroll
                for (int jj=0;jj<2;jj++)
                    acc[i][jj] = __builtin_amdgcn_mfma_f32_16x16x32_bf16(af[i], bfv[jj], acc[i][jj], 0,0,0);
            __syncthreads();
        }
    }
    #pragma unroll
    for (int i=0;i<2;i++){
        #pragma unroll
        for (int jj=0;jj<2;jj++){
            int n = nw + jj*16 + lm;
            int yy = y0 + (n>>4), xx = n&15;
            size_t opos = ((size_t)(2*zp+oz)<<10) + ((size_t)(2*yy+oy)<<5) + (2*xx+ox);
            #pragma unroll
            for (int r=0;r<4;r++){
                int co = mw + i*16 + lq*4 + r;
                U[(size_t)co*S3 + opos] = acc[i][jj][r];
            }
        }
    }
}

// ---------------- 3x3x3 conv via MFMA, m97-style async dbuf staging ----------------
// Block: M=128 (mt half of co), N=128 (4 y-rows x 32 x), fixed z. 189 k-steps (tap x cb).
// Per step: 4 global_load_lds dwordx4 into buf^1, 8 ds_read_b128 + 16 MFMA from buf.
__global__ __launch_bounds__(256,2) void conv_mfma_kernel(const unsigned short* __restrict__ Xp,
        const unsigned short* __restrict__ Wt, const float* __restrict__ bg,
        float* __restrict__ Y){
    __shared__ unsigned short sA[2][4096];   // 128 co x 32 ci
    __shared__ unsigned short sB[2][4096];   // 128 px x 32 ci
    const int nt = blockIdx.x;     // 0..255: z(32) x ygrp(8)
    const int mt = blockIdx.y;     // 0..1
    const int z  = nt >> 3;
    const int y0 = (nt & 7) * 4;
    const int t = threadIdx.x, w = t>>6, l = t&63;
    const int mw = (w & 1) * 64, nw = (w >> 1) * 64;
    const int lm = l & 15, lq = l >> 4;
    const int wbase = (t & 192) * 8;          // wave-uniform LDS base (shorts)
    const int p0 = t >> 2, q8 = (t & 3) * 8;  // staging chunk: pixel/co row + 8-ci part
    const int py0 = p0 >> 5, px0 = p0 & 31;
    const size_t Bb0 = ((size_t)z*1156 + (size_t)(y0+py0)*34 + px0)*CPAD + q8;
    const size_t Bb1 = ((size_t)z*1156 + (size_t)(y0+py0+2)*34 + px0)*CPAD + q8;
    const size_t Ab  = (size_t)mt*4096 + t*8;

    floatx4 acc[4][4];
    #pragma unroll
    for (int i=0;i<4;i++)
        #pragma unroll
        for (int j=0;j<4;j++) acc[i][j] = (floatx4){0.f,0.f,0.f,0.f};

    // prologue: step 0 = (tap 0: dz=dy=dx=0, cb 0) -> soff = 0
    gld16(Xp + Bb0, &sB[0][wbase]);
    gld16(Xp + Bb1, &sB[0][2048 + wbase]);
    gld16(Wt + Ab,        &sA[0][wbase]);
    gld16(Wt + Ab + 2048, &sA[0][2048 + wbase]);

    int cur = 0;
    for (int step = 0; step < 189; ++step){
        __syncthreads();          // drains prev-issued DMA (vmcnt) + LDS reads
        int nstep = step + 1;
        if (nstep < 189){
            int ntap = nstep / 7, ncb = nstep - ntap*7;
            int dz = ntap / 9, r9 = ntap - dz*9;
            int dy = r9 / 3,   dx = r9 - dy*3;
            int soff = (dz*1156 + dy*34 + dx)*CPAD + ncb*32;
            int nb = cur ^ 1;
            gld16(Xp + Bb0 + soff, &sB[nb][wbase]);
            gld16(Xp + Bb1 + soff, &sB[nb][2048 + wbase]);
            const unsigned short* wp = Wt + (size_t)nstep*8192 + Ab;
            gld16(wp,        &sA[nb][wbase]);
            gld16(wp + 2048, &sA[nb][2048 + wbase]);
        }
        short8 af[4], bf[4];
        #pragma unroll
        for (int i=0;i<4;i++) af[i] = *(const short8*)&sA[cur][(mw + i*16 + lm)*32 + lq*8];
        #pragma unroll
        for (int j=0;j<4;j++) bf[j] = *(const short8*)&sB[cur][(nw + j*16 + lm)*32 + lq*8];
        #pragma unroll
        for (int i=0;i<4;i++)
            #pragma unroll
            for (int j=0;j<4;j++)
                acc[i][j] = __builtin_amdgcn_mfma_f32_16x16x32_bf16(af[i], bf[j], acc[i][j], 0,0,0);
        cur ^= 1;
    }
    #pragma unroll
    for (int i=0;i<4;i++){
        #pragma unroll
        for (int j=0;j<4;j++){
            const int n = nw + j*16 + lm;
            const size_t pp = ((size_t)z<<10) + ((size_t)(y0 + (n>>5))<<5) + (n&31);
            #pragma unroll
            for (int r=0;r<4;r++){
                int gm = mt*128 + mw + i*16 + lq*4 + r;
                if (gm < CC) Y[(size_t)gm*S3 + pp] = acc[i][j][r] + bg[gm];
            }
        }
    }
}

// ---------------- final 219->3 conv via MFMA, same async dbuf structure ----------------
__global__ __launch_bounds__(256,2) void convout_mfma_kernel(const unsigned short* __restrict__ Xp,
        const unsigned short* __restrict__ Wt2, const float* __restrict__ bgl,
        float* __restrict__ Y){
    __shared__ unsigned short sA[2][512];    // 16 co x 32 ci
    __shared__ unsigned short sB[2][4096];   // 128 px x 32 ci
    const int nt = blockIdx.x;      // z(32) x ygrp(8)
    const int z  = nt >> 3;
    const int y0 = (nt & 7) * 4;
    const int t = threadIdx.x, w = t>>6, l = t&63;
    const int nw = w * 32;
    const int lm = l & 15, lq = l >> 4;
    const int wbase = (t & 192) * 8;
    const int p0 = t >> 2, q8 = (t & 3) * 8;
    const int py0 = p0 >> 5, px0 = p0 & 31;
    const size_t Bb0 = ((size_t)z*1156 + (size_t)(y0+py0)*34 + px0)*CPAD + q8;
    const size_t Bb1 = ((size_t)z*1156 + (size_t)(y0+py0+2)*34 + px0)*CPAD + q8;

    floatx4 acc[2];
    acc[0] = (floatx4){0.f,0.f,0.f,0.f};
    acc[1] = (floatx4){0.f,0.f,0.f,0.f};

    gld16(Xp + Bb0, &sB[0][wbase]);
    gld16(Xp + Bb1, &sB[0][2048 + wbase]);
    if (w == 0) gld16(Wt2 + l*8, &sA[0][0]);

    int cur = 0;
    for (int step = 0; step < 189; ++step){
        __syncthreads();
        int nstep = step + 1;
        if (nstep < 189){
            int ntap = nstep / 7, ncb = nstep - ntap*7;
            int dz = ntap / 9, r9 = ntap - dz*9;
            int dy = r9 / 3,   dx = r9 - dy*3;
            int soff = (dz*1156 + dy*34 + dx)*CPAD + ncb*32;
            int nb = cur ^ 1;
            gld16(Xp + Bb0 + soff, &sB[nb][wbase]);
            gld16(Xp + Bb1 + soff, &sB[nb][2048 + wbase]);
            if (w == 0) gld16(Wt2 + (size_t)nstep*512 + l*8, &sA[nb][0]);
        }
        short8 af = *(const short8*)&sA[cur][lm*32 + lq*8];
        #pragma unroll
        for (int j=0;j<2;j++){
            short8 bf = *(const short8*)&sB[cur][(nw + j*16 + lm)*32 + lq*8];
            acc[j] = __builtin_amdgcn_mfma_f32_16x16x32_bf16(af, bf, acc[j], 0,0,0);
        }
        cur ^= 1;
    }
    if (lq == 0){
        #pragma unroll
        for (int j = 0; j < 2; j++){
            int n = nw + j*16 + lm;
            size_t pp = ((size_t)z<<10) + ((size_t)(y0 + (n>>5))<<5) + (n&31);
            #pragma unroll
            for (int r = 0; r < 3; r++)
                Y[(size_t)r*S3 + pp] = acc[j][r] + bgl[r];
        }
    }
}

extern "C" void kernel_launch(void* const* d_in, const int* in_sizes, int n_in,
                              void* d_out, int out_size, void* d_ws, size_t ws_size,
                              hipStream_t stream) {
    const float* src   = (const float*)d_in[0];
    const float* tgt   = (const float*)d_in[1];
    const float* Cmat  = (const float*)d_in[2];
    const float* up_w  = (const float*)d_in[3];
    const float* c1_w  = (const float*)d_in[5];
    const float* c1_b  = (const float*)d_in[6];
    const float* c2_w  = (const float*)d_in[7];
    const float* c2_b  = (const float*)d_in[8];
    const float* out_w = (const float*)d_in[9];
    const float* out_b = (const float*)d_in[10];

    float* out = (float*)d_out;                          // Cn [219*S3] then out [3*S3]
    char* ws = (char*)d_ws;
    unsigned short* Xp = (unsigned short*)ws;            // 34^3 x 224 bf16 = 17,608,192 B
    float*  U  = (float*)(ws + 17608192);                // 64*S3 fp32 = 8,388,608 B
    unsigned short* Wt = (unsigned short*)(ws + 17608192);       // aliases U (3,096,576 B)
    unsigned short* Cp = (unsigned short*)(ws + 25996800);       // 18^3 x 416 bf16 = 4,852,224 B
    unsigned short* Wu = (unsigned short*)(ws + 25996800 + 4852224); // 3,407,872 B
    float* srcp = (float*)(ws + 25996800);               // aliases Cp/Wu (10,061,824 B)
    unsigned short* Wt2 = (unsigned short*)(ws + 25996800); // aliases srcp after corr (193,536 B)
    float* stats = (float*)(ws + 36058624);              // 2 KB

    hipMemsetAsync(Xp, 0, 17608192, stream);             // halo + pad channels
    hipMemsetAsync(Cp, 0, 4852224, stream);

    // ---- upsample (411->64, k4 s2) as 8 parity GEMMs + instance-norm + leaky ----
    pack16_kernel<<<dim3(256,7), 256, 0, stream>>>(Cmat, Cp);
    wupack_kernel<<<6656, 256, 0, stream>>>(up_w, Wu);
    ups_mfma_kernel<<<512, 256, 0, stream>>>(Cp, Wu, U);
    stats_kernel<<<64, 256, 0, stream>>>(U, stats, 64);
    pack_kernel<<<dim3(1024,1), 256, 0, stream>>>(U, stats, stats+64, Xp, 64, 128, 1); // Cup -> ch 128..191
    // ---- concat: tgt -> ch 0..63, src -> ch 64..127 (raw) ----
    pack_kernel<<<dim3(1024,1), 256, 0, stream>>>(tgt, nullptr, nullptr, Xp, 64, 0, 0);
    pack_kernel<<<dim3(1024,1), 256, 0, stream>>>(src, nullptr, nullptr, Xp, 64, 64, 0);
    // ---- correlation volume -> ch 192..218 ----
    pad_kernel<<<9826, 256, 0, stream>>>(src, srcp);
    corr_kernel<<<128, 256, 0, stream>>>(tgt, srcp, Xp);
    // ---- out-conv weight pack (srcp region is free after corr) ----
    wpack_out_kernel<<<378, 256, 0, stream>>>(out_w, Wt2);
    // ---- conv1 (219->219) MFMA ----
    wpack_kernel<<<6048, 256, 0, stream>>>(c1_w, Wt, 1);
    conv_mfma_kernel<<<dim3(256,2), 256, 0, stream>>>(Xp, Wt, c1_b, out);
    stats_kernel<<<219, 256, 0, stream>>>(out, stats, 219);
    pack_kernel<<<dim3(1024,4), 256, 0, stream>>>(out, stats, stats+219, Xp, 219, 0, 1);
    // ---- conv2 (219->219) MFMA ----
    wpack_kernel<<<6048, 256, 0, stream>>>(c2_w, Wt, 0);
    conv_mfma_kernel<<<dim3(256,2), 256, 0, stream>>>(Xp, Wt, c2_b, out);
    // ---- norm + leaky: fp32 Cn to d_out, bf16 packed Cn to Xp ----
    stats_kernel<<<219, 256, 0, stream>>>(out, stats, 219);
    pack_kernel<<<dim3(1024,4), 256, 0, stream>>>(out, stats, stats+219, Xp, 219, 0, 1);
    norm_apply_kernel<<<(219*(S3/4))/256, 256, 0, stream>>>(out, stats, out, 219);
    // ---- final 219->3 conv via MFMA ----
    convout_mfma_kernel<<<256, 256, 0, stream>>>(Xp, Wt2, out_b, out + (size_t)CC*S3);
}

// Round 6
// 660.233 us; speedup vs baseline: 1.4461x; 1.2252x over previous
//
#include <hip/hip_runtime.h>
#include <hip/hip_bf16.h>

#define S3 32768          // 32^3
#define PADD 34
#define PADS (34*34*34)   // 39304
#define CC 219
#define CF 64
#define CPAD 224          // padded channel count for conv inputs
#define CIN_UP 411
#define CUPAD 416         // padded channel count for upsample input
#define ALPHA 0.1f
#define EPS_IN 1e-5f

typedef __attribute__((ext_vector_type(8))) short short8;   // 8 bf16 (4 VGPRs)
typedef __attribute__((ext_vector_type(4))) float floatx4;  // 4 fp32 acc

__device__ __forceinline__ float lrelu(float v){ return v >= 0.f ? v : ALPHA * v; }
__device__ __forceinline__ unsigned short f2bf(float f){
    unsigned int u = __builtin_bit_cast(unsigned int, f);
    u = (u + 0x7FFFu + ((u >> 16) & 1u)) >> 16;   // RNE
    return (unsigned short)u;
}
// barrier that only drains LDS ops: global-load prefetch stays in flight (AITER pattern)
#define LGKM_BARRIER() __asm__ __volatile__("s_waitcnt lgkmcnt(0)\ns_barrier" ::: "memory")

// ---------------- zero-pad src to [64][34][34][34] fp32 (for corr) ----------------
__global__ __launch_bounds__(256) void pad_kernel(const float* __restrict__ src,
                                                  float* __restrict__ dst){
    int idx = blockIdx.x * 256 + threadIdx.x;
    if (idx >= CF * PADS) return;
    int c = idx / PADS, r = idx % PADS;
    int z = r / (PADD*PADD); int r2 = r % (PADD*PADD);
    int y = r2 / PADD, x = r2 % PADD;
    float v = 0.f;
    if (z >= 1 && z <= 32 && y >= 1 && y <= 32 && x >= 1 && x <= 32)
        v = src[((c*32 + (z-1))*32 + (y-1))*32 + (x-1)];
    dst[idx] = v;
}

// ---------------- correlation volume -> Xp channels [192..219) bf16 ----------------
__global__ __launch_bounds__(256) void corr_kernel(const float* __restrict__ tgt,
                                                   const float* __restrict__ srcp,
                                                   unsigned short* __restrict__ Xp){
    int p = blockIdx.x * 256 + threadIdx.x;   // 0..32767
    int z = p >> 10, y = (p >> 5) & 31, x = p & 31;
    float acc[27];
    #pragma unroll
    for (int k = 0; k < 27; k++) acc[k] = 0.f;
    int pbase = ((z+1)*PADD + (y+1))*PADD + (x+1);
    for (int c = 0; c < CF; c++){
        float t = tgt[c*S3 + p];
        const float* sp = srcp + c*PADS + pbase;
        #pragma unroll
        for (int dz = 0; dz < 3; dz++)
            #pragma unroll
            for (int dy = 0; dy < 3; dy++)
                #pragma unroll
                for (int dx = 0; dx < 3; dx++){
                    int k = (dz*3 + dy)*3 + dx;
                    acc[k] += t * sp[(dz-1)*(PADD*PADD) + (dy-1)*PADD + (dx-1)];
                }
    }
    unsigned short cv[27];
    #pragma unroll
    for (int k = 0; k < 27; k++) cv[k] = f2bf(acc[k] * (1.f/64.f));
    size_t bi = ((size_t)(z+1)*1156 + (y+1)*34 + (x+1))*CPAD + 192;
    uint4 o0, o1, o2;
    o0.x = cv[0]  | ((unsigned)cv[1]<<16);  o0.y = cv[2]  | ((unsigned)cv[3]<<16);
    o0.z = cv[4]  | ((unsigned)cv[5]<<16);  o0.w = cv[6]  | ((unsigned)cv[7]<<16);
    o1.x = cv[8]  | ((unsigned)cv[9]<<16);  o1.y = cv[10] | ((unsigned)cv[11]<<16);
    o1.z = cv[12] | ((unsigned)cv[13]<<16); o1.w = cv[14] | ((unsigned)cv[15]<<16);
    o2.x = cv[16] | ((unsigned)cv[17]<<16); o2.y = cv[18] | ((unsigned)cv[19]<<16);
    o2.z = cv[20] | ((unsigned)cv[21]<<16); o2.w = cv[22] | ((unsigned)cv[23]<<16);
    *(uint4*)&Xp[bi]      = o0;
    *(uint4*)&Xp[bi + 8]  = o1;
    *(uint4*)&Xp[bi + 16] = o2;
    *(unsigned int*)&Xp[bi + 24] = cv[24] | ((unsigned)cv[25]<<16);
    Xp[bi + 26] = cv[26];
}

// ---------------- instance-norm stats: one block per channel ----------------
__global__ __launch_bounds__(256) void stats_kernel(const float* __restrict__ xin,
                                                    float* __restrict__ stats, int nch){
    int c = blockIdx.x;
    const float* p = xin + (size_t)c * S3;
    float s = 0.f, s2 = 0.f;
    for (int i = threadIdx.x; i < S3; i += 256){
        float v = p[i];
        s += v; s2 += v*v;
    }
    #pragma unroll
    for (int off = 32; off > 0; off >>= 1){
        s  += __shfl_xor(s,  off);
        s2 += __shfl_xor(s2, off);
    }
    __shared__ float ls[4], ls2[4];
    int wid = threadIdx.x >> 6;
    if ((threadIdx.x & 63) == 0){ ls[wid] = s; ls2[wid] = s2; }
    __syncthreads();
    if (threadIdx.x == 0){
        float S = 0.f, S2 = 0.f;
        #pragma unroll
        for (int w = 0; w < 4; w++){ S += ls[w]; S2 += ls2[w]; }
        float m   = S * (1.f/S3);
        float var = S2 * (1.f/S3) - m*m;
        stats[c]       = m;
        stats[nch + c] = rsqrtf(var + EPS_IN);
    }
}

// ---------------- apply instance-norm + leaky (fp32, for final Cn) ----------------
__global__ __launch_bounds__(256) void norm_apply_kernel(const float* __restrict__ xin,
                                                         const float* __restrict__ stats,
                                                         float* __restrict__ xout, int nch){
    int idx = blockIdx.x * 256 + threadIdx.x;       // float4 units
    int n4  = nch * (S3/4);
    if (idx >= n4) return;
    int c = idx >> 13;
    float m = stats[c], r = stats[nch + c];
    float4 v = ((const float4*)xin)[idx];
    v.x = lrelu((v.x - m) * r);
    v.y = lrelu((v.y - m) * r);
    v.z = lrelu((v.z - m) * r);
    v.w = lrelu((v.w - m) * r);
    ((float4*)xout)[idx] = v;
}

// ---------------- pack fp32 [C][32^3] -> channel-last bf16 Xp[34^3][224] ----------------
__global__ __launch_bounds__(256) void pack_kernel(const float* __restrict__ src,
        const float* __restrict__ mean, const float* __restrict__ rstd,
        unsigned short* __restrict__ Xp, int Csrc, int dstbase, int donorm){
    __shared__ float sT[64*33];
    const int row = blockIdx.x;          // z*32+y
    const int chunk = blockIdx.y;
    const int t = threadIdx.x;
    {
        int c = t >> 2, xq = (t & 3) * 8;
        int csrc = chunk*64 + c;
        float4 v0 = make_float4(0.f,0.f,0.f,0.f), v1 = v0;
        float m = 0.f, r = 1.f;
        if (csrc < Csrc){
            const float4* s4 = (const float4*)&src[(size_t)csrc*S3 + row*32 + xq];
            v0 = s4[0]; v1 = s4[1];
            if (donorm){ m = mean[csrc]; r = rstd[csrc]; }
        }
        if (donorm){
            v0.x = lrelu((v0.x-m)*r); v0.y = lrelu((v0.y-m)*r);
            v0.z = lrelu((v0.z-m)*r); v0.w = lrelu((v0.w-m)*r);
            v1.x = lrelu((v1.x-m)*r); v1.y = lrelu((v1.y-m)*r);
            v1.z = lrelu((v1.z-m)*r); v1.w = lrelu((v1.w-m)*r);
        }
        float* sp = &sT[c*33 + xq];
        sp[0]=v0.x; sp[1]=v0.y; sp[2]=v0.z; sp[3]=v0.w;
        sp[4]=v1.x; sp[5]=v1.y; sp[6]=v1.z; sp[7]=v1.w;
    }
    __syncthreads();
    {
        int x = t >> 3, coff = (t & 7) * 8;
        int dstc = dstbase + chunk*64 + coff;
        if (dstc < CPAD){
            unsigned short u[8];
            #pragma unroll
            for (int j = 0; j < 8; j++) u[j] = f2bf(sT[(coff+j)*33 + x]);
            uint4 o;
            o.x = u[0] | ((unsigned)u[1]<<16);
            o.y = u[2] | ((unsigned)u[3]<<16);
            o.z = u[4] | ((unsigned)u[5]<<16);
            o.w = u[6] | ((unsigned)u[7]<<16);
            int z = row >> 5, y = row & 31;
            size_t pos = (size_t)(z+1)*1156 + (y+1)*34 + (x+1);
            *(uint4*)&Xp[pos*CPAD + dstc] = o;
        }
    }
}

// ---------------- pack fp32 [411][16^3] -> channel-last bf16 Cp[18^3][416] ----------------
__global__ __launch_bounds__(256) void pack16_kernel(const float* __restrict__ src,
        unsigned short* __restrict__ Cp){
    __shared__ float sT[64*17];
    const int row = blockIdx.x;   // z'*16+y'
    const int chunk = blockIdx.y; // 0..6
    const int t = threadIdx.x;
    {
        int c = t >> 2, xq = (t & 3) * 4;
        int csrc = chunk*64 + c;
        float4 v = make_float4(0.f,0.f,0.f,0.f);
        if (csrc < CIN_UP)
            v = *(const float4*)&src[(size_t)csrc*4096 + row*16 + xq];
        float* sp = &sT[c*17 + xq];
        sp[0]=v.x; sp[1]=v.y; sp[2]=v.z; sp[3]=v.w;
    }
    __syncthreads();
    {
        int x = t >> 4, coff = (t & 15) * 4;
        int dstc = chunk*64 + coff;
        if (dstc < CUPAD){
            unsigned short u0 = f2bf(sT[(coff+0)*17 + x]);
            unsigned short u1 = f2bf(sT[(coff+1)*17 + x]);
            unsigned short u2 = f2bf(sT[(coff+2)*17 + x]);
            unsigned short u3 = f2bf(sT[(coff+3)*17 + x]);
            uint2 o; o.x = u0 | ((unsigned)u1<<16); o.y = u2 | ((unsigned)u3<<16);
            int z = row >> 4, y = row & 15;
            size_t pos = (size_t)(z+1)*324 + (y+1)*18 + (x+1);
            *(uint2*)&Cp[pos*CUPAD + dstc] = o;
        }
    }
}

// ---------------- pack conv weights: Wt[step=tap*7+cb][co 256][ci 32] bf16 ----------------
__global__ __launch_bounds__(256) void wpack_kernel(const float* __restrict__ w,
        unsigned short* __restrict__ Wt, int perm){
    int idx = blockIdx.x*256 + threadIdx.x;   // < 27*7*256*32
    int ciin = idx & 31;
    int co   = (idx >> 5) & 255;
    int rest = idx >> 13;        // tap*7+cb
    int cb = rest % 7, tap = rest / 7;
    int ci = cb*32 + ciin;
    float v = 0.f;
    if (co < CC && ci < CC){
        int ciref = ci;
        if (perm) ciref = ci < 128 ? ci : (ci < 192 ? ci + 27 : ci - 64);
        v = w[((size_t)co*CC + ciref)*27 + tap];
    }
    Wt[idx] = f2bf(v);
}

// ---------------- pack out-conv weights: Wt2[tap][cb][co 16][ci 32] bf16 ----------------
__global__ __launch_bounds__(256) void wpack_out_kernel(const float* __restrict__ w,
        unsigned short* __restrict__ Wt2){
    int idx = blockIdx.x*256 + threadIdx.x;   // < 27*7*16*32 = 96768
    if (idx >= 27*7*16*32) return;
    int ciin = idx & 31;
    int co   = (idx >> 5) & 15;
    int rest = idx >> 9;        // tap*7+cb
    int cb = rest % 7, tap = rest / 7;
    int ci = cb*32 + ciin;
    float v = 0.f;
    if (co < 3 && ci < CC)
        v = w[((size_t)co*CC + ci)*27 + tap];
    Wt2[idx] = f2bf(v);
}

// ---------------- pack upsample weights: Wu[parity 8][tap 8][co 64][ci 416] bf16 ----------------
__global__ __launch_bounds__(256) void wupack_kernel(const float* __restrict__ w,
        unsigned short* __restrict__ Wu){
    int idx = blockIdx.x*256 + threadIdx.x;  // < 8*8*64*416
    int ci = idx % CUPAD;
    int rest = idx / CUPAD;
    int co = rest & 63;
    int pj = rest >> 6;
    int j = pj & 7, p = pj >> 3;
    float v = 0.f;
    if (ci < CIN_UP){
        int oz = p>>2, oy = (p>>1)&1, ox = p&1;
        int jz = j>>2, jy = (j>>1)&1, jx = j&1;
        int wz = 3 - oz - 2*jz, wy = 3 - oy - 2*jy, wx = 3 - ox - 2*jx;
        v = w[(((size_t)ci*64 + co)*64) + wz*16 + wy*4 + wx];
    }
    Wu[idx] = f2bf(v);
}

// ---------------- upsample via MFMA: per-parity GEMM M=64, N=16^3, K=8*416 ----------------
__global__ __launch_bounds__(256,2) void ups_mfma_kernel(const unsigned short* __restrict__ Cp,
        const unsigned short* __restrict__ Wu, float* __restrict__ U){
    __shared__ unsigned short sA[64*40];
    __shared__ unsigned short sB[64*40];
    const int nt = blockIdx.x;          // 512 = parity(8) x z'(16) x ygrp(4)
    const int p  = nt >> 6;
    const int zp = (nt >> 2) & 15;
    const int y0 = (nt & 3) * 4;
    const int oz = p>>2, oy = (p>>1)&1, ox = p&1;
    const int t = threadIdx.x, w = t>>6, l = t&63;
    const int mw = (w&1)*32, nw = (w>>1)*32;
    const int lm = l&15, lq = l>>4;
    const int sn = t>>2, spart = (t&3)*8;
    const int sr = sn>>4, sx = sn&15;
    floatx4 acc[2][2];
    #pragma unroll
    for (int i=0;i<2;i++)
        #pragma unroll
        for (int j=0;j<2;j++) acc[i][j] = (floatx4){0.f,0.f,0.f,0.f};

    for (int j = 0; j < 8; ++j){
        int sz = oz + (j>>2), sy = oy + ((j>>1)&1), sxx = ox + (j&1);
        size_t pbase = ((size_t)(zp+sz)*324 + (y0+sr+sy)*18 + (sx+sxx)) * CUPAD;
        size_t abase = ((size_t)(p*8 + j)*64 + sn)*CUPAD;
        for (int cb = 0; cb < 13; ++cb){
            uint4 av = *(const uint4*)&Wu[abase + cb*32 + spart];
            uint4 bv = *(const uint4*)&Cp[pbase + cb*32 + spart];
            *(uint4*)&sA[sn*40 + spart] = av;
            *(uint4*)&sB[sn*40 + spart] = bv;
            __syncthreads();
            short8 af[2], bfv[2];
            #pragma unroll
            for (int i=0;i<2;i++){
                af[i]  = *(const short8*)&sA[(mw + i*16 + lm)*40 + lq*8];
                bfv[i] = *(const short8*)&sB[(nw + i*16 + lm)*40 + lq*8];
            }
            #pragma unroll
            for (int i=0;i<2;i++)
                #pragma unroll
                for (int jj=0;jj<2;jj++)
                    acc[i][jj] = __builtin_amdgcn_mfma_f32_16x16x32_bf16(af[i], bfv[jj], acc[i][jj], 0,0,0);
            __syncthreads();
        }
    }
    #pragma unroll
    for (int i=0;i<2;i++){
        #pragma unroll
        for (int jj=0;jj<2;jj++){
            int n = nw + jj*16 + lm;
            int yy = y0 + (n>>4), xx = n&15;
            size_t opos = ((size_t)(2*zp+oz)<<10) + ((size_t)(2*yy+oy)<<5) + (2*xx+ox);
            #pragma unroll
            for (int r=0;r<4;r++){
                int co = mw + i*16 + lq*4 + r;
                U[(size_t)co*S3 + opos] = acc[i][jj][r];
            }
        }
    }
}

// ---------------- 3x3x3 conv via MFMA: reg-A + LDS-dbuf-B + lgkm-only barrier ----------------
// A-frags direct global->VGPR (rotating, 1-step prefetch, survives barrier via fine vmcnt).
// B staged global->VGPR->ds_write, double-buffered, stride-36 rows (conflict-free b128).
__global__ __launch_bounds__(256,2) void conv_mfma_kernel(const unsigned short* __restrict__ Xp,
        const unsigned short* __restrict__ Wt, const float* __restrict__ bg,
        float* __restrict__ Y){
    __shared__ unsigned short sB[2][128*36];   // 2 x 9216 B
    const int nt = blockIdx.x;     // 0..255: z(32) x ygrp(8)
    const int mt = blockIdx.y;     // 0..1
    const int z  = nt >> 3;
    const int y0 = (nt & 7) * 4;
    const int t = threadIdx.x, w = t>>6, l = t&63;
    const int mw = (w & 1) * 64, nw = (w >> 1) * 64;
    const int lm = l & 15, lq = l >> 4;
    const int p0 = t >> 2, q8 = (t & 3) * 8;
    const int py0 = p0 >> 5, px0 = p0 & 31;
    const size_t Bb0 = ((size_t)z*1156 + (size_t)(y0+py0)*34 + px0)*CPAD + q8;
    const size_t Bb1 = ((size_t)z*1156 + (size_t)(y0+py0+2)*34 + px0)*CPAD + q8;
    const int sO0 = p0*36 + q8, sO1 = (p0+64)*36 + q8;
    const unsigned short* ap = Wt + (size_t)(mt*128 + mw + lm)*32 + lq*8;

    floatx4 acc[4][4];
    #pragma unroll
    for (int i=0;i<4;i++)
        #pragma unroll
        for (int j=0;j<4;j++) acc[i][j] = (floatx4){0.f,0.f,0.f,0.f};

    // prologue: step 0 (tap0, cb0 -> offsets 0). B loads issued BEFORE A loads (vmcnt FIFO order).
    uint4 c0 = *(const uint4*)(Xp + Bb0);
    uint4 c1 = *(const uint4*)(Xp + Bb1);
    short8 afc0 = *(const short8*)(ap);
    short8 afc1 = *(const short8*)(ap + 512);
    short8 afc2 = *(const short8*)(ap + 1024);
    short8 afc3 = *(const short8*)(ap + 1536);
    *(uint4*)&sB[0][sO0] = c0;
    *(uint4*)&sB[0][sO1] = c1;
    LGKM_BARRIER();

    int cur = 0;
    for (int step = 0; step < 189; ++step){
        const int nstep = step + 1;
        uint4 n0, n1; short8 an0, an1, an2, an3;
        if (nstep < 189){
            int ntap = nstep / 7, ncb = nstep - ntap*7;
            int dz = ntap / 9, r9 = ntap - dz*9;
            int dy = r9 / 3,   dx = r9 - dy*3;
            size_t soff = (size_t)((dz*1156 + dy*34 + dx)*CPAD + ncb*32);
            n0 = *(const uint4*)(Xp + Bb0 + soff);          // B first
            n1 = *(const uint4*)(Xp + Bb1 + soff);
            const unsigned short* apn = ap + (size_t)nstep*8192;
            an0 = *(const short8*)(apn);                    // then A
            an1 = *(const short8*)(apn + 512);
            an2 = *(const short8*)(apn + 1024);
            an3 = *(const short8*)(apn + 1536);
        }
        short8 bf[4];
        #pragma unroll
        for (int j=0;j<4;j++) bf[j] = *(const short8*)&sB[cur][(nw + j*16 + lm)*36 + lq*8];
        {
            short8 af[4] = {afc0, afc1, afc2, afc3};
            #pragma unroll
            for (int i=0;i<4;i++)
                #pragma unroll
                for (int j=0;j<4;j++)
                    acc[i][j] = __builtin_amdgcn_mfma_f32_16x16x32_bf16(af[i], bf[j], acc[i][j], 0,0,0);
        }
        if (nstep < 189){
            *(uint4*)&sB[cur^1][sO0] = n0;   // waits vmcnt for B only (A behind it in FIFO)
            *(uint4*)&sB[cur^1][sO1] = n1;
            afc0 = an0; afc1 = an1; afc2 = an2; afc3 = an3;
        }
        LGKM_BARRIER();
        cur ^= 1;
    }
    #pragma unroll
    for (int i=0;i<4;i++){
        #pragma unroll
        for (int j=0;j<4;j++){
            const int n = nw + j*16 + lm;
            const size_t pp = ((size_t)z<<10) + ((size_t)(y0 + (n>>5))<<5) + (n&31);
            #pragma unroll
            for (int r=0;r<4;r++){
                int gm = mt*128 + mw + i*16 + lq*4 + r;
                if (gm < CC) Y[(size_t)gm*S3 + pp] = acc[i][j][r] + bg[gm];
            }
        }
    }
}

// ---------------- final 219->3 conv: persistent spatial B tile, reg-A (27 frags), 14 barriers ----------------
__global__ __launch_bounds__(256,2) void convout_mfma_kernel(const unsigned short* __restrict__ Xp,
        const unsigned short* __restrict__ Wt2, const float* __restrict__ bgl,
        float* __restrict__ Y){
    __shared__ unsigned short sB[612*36];   // 44,064 B: [3z][6y][34x] x 32ci (stride 36)
    const int nt = blockIdx.x;      // z(32) x ygrp(8)
    const int z  = nt >> 3;
    const int y0 = (nt & 7) * 4;
    const int t = threadIdx.x, w = t>>6, l = t&63;
    const int nw = w * 32;
    const int lm = l & 15, lq = l >> 4;
    floatx4 acc[2];
    acc[0] = (floatx4){0.f,0.f,0.f,0.f};
    acc[1] = (floatx4){0.f,0.f,0.f,0.f};

    for (int cb = 0; cb < 7; ++cb){
        __syncthreads();
        for (int idx = t; idx < 2448; idx += 256){
            int p = idx >> 2, q = idx & 3;
            int zz = p / 204, rem = p % 204;
            int yy = rem / 34, x = rem - yy*34;
            uint4 v = *(const uint4*)&Xp[((size_t)((z+zz)*1156 + (y0+yy)*34 + x))*CPAD + cb*32 + q*8];
            *(uint4*)&sB[p*36 + q*8] = v;
        }
        short8 af[27];
        {
            const unsigned short* wp = Wt2 + ((size_t)(cb*16 + lm))*32 + lq*8;
            #pragma unroll
            for (int tap = 0; tap < 27; ++tap)
                af[tap] = *(const short8*)(wp + (size_t)tap*3584);   // 7*16*32 per tap
        }
        __syncthreads();
        #pragma unroll
        for (int tap = 0; tap < 27; ++tap){
            const int dz = tap/9, dy = (tap/3)%3, dx = tap%3;
            #pragma unroll
            for (int j=0;j<2;j++){
                int n = nw + j*16 + lm;
                int r = n >> 5, x = n & 31;
                short8 bf = *(const short8*)&sB[(dz*204 + (r+dy)*34 + (x+dx))*36 + lq*8];
                acc[j] = __builtin_amdgcn_mfma_f32_16x16x32_bf16(af[tap], bf, acc[j], 0,0,0);
            }
        }
    }
    if (lq == 0){
        #pragma unroll
        for (int j = 0; j < 2; j++){
            int n = nw + j*16 + lm;
            size_t pp = ((size_t)z<<10) + ((size_t)(y0 + (n>>5))<<5) + (n&31);
            #pragma unroll
            for (int r = 0; r < 3; r++)
                Y[(size_t)r*S3 + pp] = acc[j][r] + bgl[r];
        }
    }
}

extern "C" void kernel_launch(void* const* d_in, const int* in_sizes, int n_in,
                              void* d_out, int out_size, void* d_ws, size_t ws_size,
                              hipStream_t stream) {
    const float* src   = (const float*)d_in[0];
    const float* tgt   = (const float*)d_in[1];
    const float* Cmat  = (const float*)d_in[2];
    const float* up_w  = (const float*)d_in[3];
    const float* c1_w  = (const float*)d_in[5];
    const float* c1_b  = (const float*)d_in[6];
    const float* c2_w  = (const float*)d_in[7];
    const float* c2_b  = (const float*)d_in[8];
    const float* out_w = (const float*)d_in[9];
    const float* out_b = (const float*)d_in[10];

    float* out = (float*)d_out;                          // Cn [219*S3] then out [3*S3]
    char* ws = (char*)d_ws;
    unsigned short* Xp = (unsigned short*)ws;            // 34^3 x 224 bf16 = 17,608,192 B
    float*  U  = (float*)(ws + 17608192);                // 64*S3 fp32 = 8,388,608 B
    unsigned short* Wt = (unsigned short*)(ws + 17608192);       // aliases U (3,096,576 B)
    unsigned short* Cp = (unsigned short*)(ws + 25996800);       // 18^3 x 416 bf16 = 4,852,224 B
    unsigned short* Wu = (unsigned short*)(ws + 25996800 + 4852224); // 3,407,872 B
    float* srcp = (float*)(ws + 25996800);               // aliases Cp/Wu (10,061,824 B)
    unsigned short* Wt2 = (unsigned short*)(ws + 25996800); // aliases srcp after corr (193,536 B)
    float* stats = (float*)(ws + 36058624);              // 2 KB

    hipMemsetAsync(Xp, 0, 17608192, stream);             // halo + pad channels
    hipMemsetAsync(Cp, 0, 4852224, stream);

    // ---- upsample (411->64, k4 s2) as 8 parity GEMMs + instance-norm + leaky ----
    pack16_kernel<<<dim3(256,7), 256, 0, stream>>>(Cmat, Cp);
    wupack_kernel<<<6656, 256, 0, stream>>>(up_w, Wu);
    ups_mfma_kernel<<<512, 256, 0, stream>>>(Cp, Wu, U);
    stats_kernel<<<64, 256, 0, stream>>>(U, stats, 64);
    pack_kernel<<<dim3(1024,1), 256, 0, stream>>>(U, stats, stats+64, Xp, 64, 128, 1); // Cup -> ch 128..191
    // ---- concat: tgt -> ch 0..63, src -> ch 64..127 (raw) ----
    pack_kernel<<<dim3(1024,1), 256, 0, stream>>>(tgt, nullptr, nullptr, Xp, 64, 0, 0);
    pack_kernel<<<dim3(1024,1), 256, 0, stream>>>(src, nullptr, nullptr, Xp, 64, 64, 0);
    // ---- correlation volume -> ch 192..218 ----
    pad_kernel<<<9826, 256, 0, stream>>>(src, srcp);
    corr_kernel<<<128, 256, 0, stream>>>(tgt, srcp, Xp);
    // ---- out-conv weight pack (srcp region is free after corr) ----
    wpack_out_kernel<<<378, 256, 0, stream>>>(out_w, Wt2);
    // ---- conv1 (219->219) MFMA ----
    wpack_kernel<<<6048, 256, 0, stream>>>(c1_w, Wt, 1);
    conv_mfma_kernel<<<dim3(256,2), 256, 0, stream>>>(Xp, Wt, c1_b, out);
    stats_kernel<<<219, 256, 0, stream>>>(out, stats, 219);
    pack_kernel<<<dim3(1024,4), 256, 0, stream>>>(out, stats, stats+219, Xp, 219, 0, 1);
    // ---- conv2 (219->219) MFMA ----
    wpack_kernel<<<6048, 256, 0, stream>>>(c2_w, Wt, 0);
    conv_mfma_kernel<<<dim3(256,2), 256, 0, stream>>>(Xp, Wt, c2_b, out);
    // ---- norm + leaky: fp32 Cn to d_out, bf16 packed Cn to Xp ----
    stats_kernel<<<219, 256, 0, stream>>>(out, stats, 219);
    pack_kernel<<<dim3(1024,4), 256, 0, stream>>>(out, stats, stats+219, Xp, 219, 0, 1);
    norm_apply_kernel<<<(219*(S3/4))/256, 256, 0, stream>>>(out, stats, out, 219);
    // ---- final 219->3 conv via MFMA ----
    convout_mfma_kernel<<<256, 256, 0, stream>>>(Xp, Wt2, out_b, out + (size_t)CC*S3);
}

// Round 7
// 566.696 us; speedup vs baseline: 1.6848x; 1.1651x over previous
//
#include <hip/hip_runtime.h>
#include <hip/hip_bf16.h>

#define S3 32768          // 32^3
#define PADD 34
#define PADS (34*34*34)   // 39304
#define CC 219
#define CF 64
#define CPAD 224          // padded channel count for conv inputs
#define CIN_UP 411
#define CUPAD 416         // padded channel count for upsample input
#define ALPHA 0.1f
#define EPS_IN 1e-5f

typedef __attribute__((ext_vector_type(8))) short short8;   // 8 bf16 (4 VGPRs)
typedef __attribute__((ext_vector_type(4))) float floatx4;  // 4 fp32 acc

__device__ __forceinline__ float lrelu(float v){ return v >= 0.f ? v : ALPHA * v; }
__device__ __forceinline__ unsigned short f2bf(float f){
    unsigned int u = __builtin_bit_cast(unsigned int, f);
    u = (u + 0x7FFFu + ((u >> 16) & 1u)) >> 16;   // RNE
    return (unsigned short)u;
}
// barrier that only drains LDS ops: global-load prefetch stays in flight (AITER pattern)
#define LGKM_BARRIER() __asm__ __volatile__("s_waitcnt lgkmcnt(0)\ns_barrier" ::: "memory")

// ---------------- zero-pad src to [64][34][34][34] fp32 (for corr) ----------------
__global__ __launch_bounds__(256) void pad_kernel(const float* __restrict__ src,
                                                  float* __restrict__ dst){
    int idx = blockIdx.x * 256 + threadIdx.x;
    if (idx >= CF * PADS) return;
    int c = idx / PADS, r = idx % PADS;
    int z = r / (PADD*PADD); int r2 = r % (PADD*PADD);
    int y = r2 / PADD, x = r2 % PADD;
    float v = 0.f;
    if (z >= 1 && z <= 32 && y >= 1 && y <= 32 && x >= 1 && x <= 32)
        v = src[((c*32 + (z-1))*32 + (y-1))*32 + (x-1)];
    dst[idx] = v;
}

// ---------------- correlation volume -> Xp channels [192..219) bf16 ----------------
__global__ __launch_bounds__(256) void corr_kernel(const float* __restrict__ tgt,
                                                   const float* __restrict__ srcp,
                                                   unsigned short* __restrict__ Xp){
    int p = blockIdx.x * 256 + threadIdx.x;   // 0..32767
    int z = p >> 10, y = (p >> 5) & 31, x = p & 31;
    float acc[27];
    #pragma unroll
    for (int k = 0; k < 27; k++) acc[k] = 0.f;
    int pbase = ((z+1)*PADD + (y+1))*PADD + (x+1);
    for (int c = 0; c < CF; c++){
        float t = tgt[c*S3 + p];
        const float* sp = srcp + c*PADS + pbase;
        #pragma unroll
        for (int dz = 0; dz < 3; dz++)
            #pragma unroll
            for (int dy = 0; dy < 3; dy++)
                #pragma unroll
                for (int dx = 0; dx < 3; dx++){
                    int k = (dz*3 + dy)*3 + dx;
                    acc[k] += t * sp[(dz-1)*(PADD*PADD) + (dy-1)*PADD + (dx-1)];
                }
    }
    unsigned short cv[27];
    #pragma unroll
    for (int k = 0; k < 27; k++) cv[k] = f2bf(acc[k] * (1.f/64.f));
    size_t bi = ((size_t)(z+1)*1156 + (y+1)*34 + (x+1))*CPAD + 192;
    uint4 o0, o1, o2;
    o0.x = cv[0]  | ((unsigned)cv[1]<<16);  o0.y = cv[2]  | ((unsigned)cv[3]<<16);
    o0.z = cv[4]  | ((unsigned)cv[5]<<16);  o0.w = cv[6]  | ((unsigned)cv[7]<<16);
    o1.x = cv[8]  | ((unsigned)cv[9]<<16);  o1.y = cv[10] | ((unsigned)cv[11]<<16);
    o1.z = cv[12] | ((unsigned)cv[13]<<16); o1.w = cv[14] | ((unsigned)cv[15]<<16);
    o2.x = cv[16] | ((unsigned)cv[17]<<16); o2.y = cv[18] | ((unsigned)cv[19]<<16);
    o2.z = cv[20] | ((unsigned)cv[21]<<16); o2.w = cv[22] | ((unsigned)cv[23]<<16);
    *(uint4*)&Xp[bi]      = o0;
    *(uint4*)&Xp[bi + 8]  = o1;
    *(uint4*)&Xp[bi + 16] = o2;
    *(unsigned int*)&Xp[bi + 24] = cv[24] | ((unsigned)cv[25]<<16);
    Xp[bi + 26] = cv[26];
}

// ---------------- instance-norm stats: one block per channel (float4 loads) ----------------
__global__ __launch_bounds__(256) void stats_kernel(const float* __restrict__ xin,
                                                    float* __restrict__ stats, int nch){
    int c = blockIdx.x;
    const float4* p = (const float4*)(xin + (size_t)c * S3);
    float s = 0.f, s2 = 0.f;
    for (int i = threadIdx.x; i < S3/4; i += 256){
        float4 v = p[i];
        s  += v.x + v.y + v.z + v.w;
        s2 += v.x*v.x + v.y*v.y + v.z*v.z + v.w*v.w;
    }
    #pragma unroll
    for (int off = 32; off > 0; off >>= 1){
        s  += __shfl_xor(s,  off);
        s2 += __shfl_xor(s2, off);
    }
    __shared__ float ls[4], ls2[4];
    int wid = threadIdx.x >> 6;
    if ((threadIdx.x & 63) == 0){ ls[wid] = s; ls2[wid] = s2; }
    __syncthreads();
    if (threadIdx.x == 0){
        float S = 0.f, S2 = 0.f;
        #pragma unroll
        for (int w = 0; w < 4; w++){ S += ls[w]; S2 += ls2[w]; }
        float m   = S * (1.f/S3);
        float var = S2 * (1.f/S3) - m*m;
        stats[c]       = m;
        stats[nch + c] = rsqrtf(var + EPS_IN);
    }
}

// ---------------- apply instance-norm + leaky (fp32, for final Cn) ----------------
__global__ __launch_bounds__(256) void norm_apply_kernel(const float* __restrict__ xin,
                                                         const float* __restrict__ stats,
                                                         float* __restrict__ xout, int nch){
    int idx = blockIdx.x * 256 + threadIdx.x;       // float4 units
    int n4  = nch * (S3/4);
    if (idx >= n4) return;
    int c = idx >> 13;
    float m = stats[c], r = stats[nch + c];
    float4 v = ((const float4*)xin)[idx];
    v.x = lrelu((v.x - m) * r);
    v.y = lrelu((v.y - m) * r);
    v.z = lrelu((v.z - m) * r);
    v.w = lrelu((v.w - m) * r);
    ((float4*)xout)[idx] = v;
}

// ---------------- pack fp32 [C][32^3] -> channel-last bf16 Xp[34^3][224] ----------------
__global__ __launch_bounds__(256) void pack_kernel(const float* __restrict__ src,
        const float* __restrict__ mean, const float* __restrict__ rstd,
        unsigned short* __restrict__ Xp, int Csrc, int dstbase, int donorm){
    __shared__ float sT[64*33];
    const int row = blockIdx.x;          // z*32+y
    const int chunk = blockIdx.y;
    const int t = threadIdx.x;
    {
        int c = t >> 2, xq = (t & 3) * 8;
        int csrc = chunk*64 + c;
        float4 v0 = make_float4(0.f,0.f,0.f,0.f), v1 = v0;
        float m = 0.f, r = 1.f;
        if (csrc < Csrc){
            const float4* s4 = (const float4*)&src[(size_t)csrc*S3 + row*32 + xq];
            v0 = s4[0]; v1 = s4[1];
            if (donorm){ m = mean[csrc]; r = rstd[csrc]; }
        }
        if (donorm){
            v0.x = lrelu((v0.x-m)*r); v0.y = lrelu((v0.y-m)*r);
            v0.z = lrelu((v0.z-m)*r); v0.w = lrelu((v0.w-m)*r);
            v1.x = lrelu((v1.x-m)*r); v1.y = lrelu((v1.y-m)*r);
            v1.z = lrelu((v1.z-m)*r); v1.w = lrelu((v1.w-m)*r);
        }
        float* sp = &sT[c*33 + xq];
        sp[0]=v0.x; sp[1]=v0.y; sp[2]=v0.z; sp[3]=v0.w;
        sp[4]=v1.x; sp[5]=v1.y; sp[6]=v1.z; sp[7]=v1.w;
    }
    __syncthreads();
    {
        int x = t >> 3, coff = (t & 7) * 8;
        int dstc = dstbase + chunk*64 + coff;
        if (dstc < CPAD){
            unsigned short u[8];
            #pragma unroll
            for (int j = 0; j < 8; j++) u[j] = f2bf(sT[(coff+j)*33 + x]);
            uint4 o;
            o.x = u[0] | ((unsigned)u[1]<<16);
            o.y = u[2] | ((unsigned)u[3]<<16);
            o.z = u[4] | ((unsigned)u[5]<<16);
            o.w = u[6] | ((unsigned)u[7]<<16);
            int z = row >> 5, y = row & 31;
            size_t pos = (size_t)(z+1)*1156 + (y+1)*34 + (x+1);
            *(uint4*)&Xp[pos*CPAD + dstc] = o;
        }
    }
}

// ---------------- pack fp32 [411][16^3] -> channel-last bf16 Cp[18^3][416] ----------------
__global__ __launch_bounds__(256) void pack16_kernel(const float* __restrict__ src,
        unsigned short* __restrict__ Cp){
    __shared__ float sT[64*17];
    const int row = blockIdx.x;   // z'*16+y'
    const int chunk = blockIdx.y; // 0..6
    const int t = threadIdx.x;
    {
        int c = t >> 2, xq = (t & 3) * 4;
        int csrc = chunk*64 + c;
        float4 v = make_float4(0.f,0.f,0.f,0.f);
        if (csrc < CIN_UP)
            v = *(const float4*)&src[(size_t)csrc*4096 + row*16 + xq];
        float* sp = &sT[c*17 + xq];
        sp[0]=v.x; sp[1]=v.y; sp[2]=v.z; sp[3]=v.w;
    }
    __syncthreads();
    {
        int x = t >> 4, coff = (t & 15) * 4;
        int dstc = chunk*64 + coff;
        if (dstc < CUPAD){
            unsigned short u0 = f2bf(sT[(coff+0)*17 + x]);
            unsigned short u1 = f2bf(sT[(coff+1)*17 + x]);
            unsigned short u2 = f2bf(sT[(coff+2)*17 + x]);
            unsigned short u3 = f2bf(sT[(coff+3)*17 + x]);
            uint2 o; o.x = u0 | ((unsigned)u1<<16); o.y = u2 | ((unsigned)u3<<16);
            int z = row >> 4, y = row & 15;
            size_t pos = (size_t)(z+1)*324 + (y+1)*18 + (x+1);
            *(uint2*)&Cp[pos*CUPAD + dstc] = o;
        }
    }
}

// ---------------- pack conv weights: Wt[step=tap*7+cb][co 256][ci 32] bf16 ----------------
__global__ __launch_bounds__(256) void wpack_kernel(const float* __restrict__ w,
        unsigned short* __restrict__ Wt, int perm){
    int idx = blockIdx.x*256 + threadIdx.x;   // < 27*7*256*32
    int ciin = idx & 31;
    int co   = (idx >> 5) & 255;
    int rest = idx >> 13;        // tap*7+cb
    int cb = rest % 7, tap = rest / 7;
    int ci = cb*32 + ciin;
    float v = 0.f;
    if (co < CC && ci < CC){
        int ciref = ci;
        if (perm) ciref = ci < 128 ? ci : (ci < 192 ? ci + 27 : ci - 64);
        v = w[((size_t)co*CC + ciref)*27 + tap];
    }
    Wt[idx] = f2bf(v);
}

// ---------------- pack out-conv weights: Wt2[tap][cb][co 16][ci 32] bf16 ----------------
__global__ __launch_bounds__(256) void wpack_out_kernel(const float* __restrict__ w,
        unsigned short* __restrict__ Wt2){
    int idx = blockIdx.x*256 + threadIdx.x;   // < 27*7*16*32 = 96768
    if (idx >= 27*7*16*32) return;
    int ciin = idx & 31;
    int co   = (idx >> 5) & 15;
    int rest = idx >> 9;        // tap*7+cb
    int cb = rest % 7, tap = rest / 7;
    int ci = cb*32 + ciin;
    float v = 0.f;
    if (co < 3 && ci < CC)
        v = w[((size_t)co*CC + ci)*27 + tap];
    Wt2[idx] = f2bf(v);
}

// ---------------- pack upsample weights: Wu[parity 8][tap 8][co 64][ci 416] bf16 ----------------
__global__ __launch_bounds__(256) void wupack_kernel(const float* __restrict__ w,
        unsigned short* __restrict__ Wu){
    int idx = blockIdx.x*256 + threadIdx.x;  // < 8*8*64*416
    int ci = idx % CUPAD;
    int rest = idx / CUPAD;
    int co = rest & 63;
    int pj = rest >> 6;
    int j = pj & 7, p = pj >> 3;
    float v = 0.f;
    if (ci < CIN_UP){
        int oz = p>>2, oy = (p>>1)&1, ox = p&1;
        int jz = j>>2, jy = (j>>1)&1, jx = j&1;
        int wz = 3 - oz - 2*jz, wy = 3 - oy - 2*jy, wx = 3 - ox - 2*jx;
        v = w[(((size_t)ci*64 + co)*64) + wz*16 + wy*4 + wx];
    }
    Wu[idx] = f2bf(v);
}

// ---------------- upsample via MFMA: per-parity GEMM M=64, N=16^3, K=8*416 ----------------
__global__ __launch_bounds__(256,2) void ups_mfma_kernel(const unsigned short* __restrict__ Cp,
        const unsigned short* __restrict__ Wu, float* __restrict__ U){
    __shared__ unsigned short sA[64*40];
    __shared__ unsigned short sB[64*40];
    const int nt = blockIdx.x;          // 512 = parity(8) x z'(16) x ygrp(4)
    const int p  = nt >> 6;
    const int zp = (nt >> 2) & 15;
    const int y0 = (nt & 3) * 4;
    const int oz = p>>2, oy = (p>>1)&1, ox = p&1;
    const int t = threadIdx.x, w = t>>6, l = t&63;
    const int mw = (w&1)*32, nw = (w>>1)*32;
    const int lm = l&15, lq = l>>4;
    const int sn = t>>2, spart = (t&3)*8;
    const int sr = sn>>4, sx = sn&15;
    floatx4 acc[2][2];
    #pragma unroll
    for (int i=0;i<2;i++)
        #pragma unroll
        for (int j=0;j<2;j++) acc[i][j] = (floatx4){0.f,0.f,0.f,0.f};

    for (int j = 0; j < 8; ++j){
        int sz = oz + (j>>2), sy = oy + ((j>>1)&1), sxx = ox + (j&1);
        size_t pbase = ((size_t)(zp+sz)*324 + (y0+sr+sy)*18 + (sx+sxx)) * CUPAD;
        size_t abase = ((size_t)(p*8 + j)*64 + sn)*CUPAD;
        for (int cb = 0; cb < 13; ++cb){
            uint4 av = *(const uint4*)&Wu[abase + cb*32 + spart];
            uint4 bv = *(const uint4*)&Cp[pbase + cb*32 + spart];
            *(uint4*)&sA[sn*40 + spart] = av;
            *(uint4*)&sB[sn*40 + spart] = bv;
            __syncthreads();
            short8 af[2], bfv[2];
            #pragma unroll
            for (int i=0;i<2;i++){
                af[i]  = *(const short8*)&sA[(mw + i*16 + lm)*40 + lq*8];
                bfv[i] = *(const short8*)&sB[(nw + i*16 + lm)*40 + lq*8];
            }
            #pragma unroll
            for (int i=0;i<2;i++)
                #pragma unroll
                for (int jj=0;jj<2;jj++)
                    acc[i][jj] = __builtin_amdgcn_mfma_f32_16x16x32_bf16(af[i], bfv[jj], acc[i][jj], 0,0,0);
            __syncthreads();
        }
    }
    #pragma unroll
    for (int i=0;i<2;i++){
        #pragma unroll
        for (int jj=0;jj<2;jj++){
            int n = nw + jj*16 + lm;
            int yy = y0 + (n>>4), xx = n&15;
            size_t opos = ((size_t)(2*zp+oz)<<10) + ((size_t)(2*yy+oy)<<5) + (2*xx+ox);
            #pragma unroll
            for (int r=0;r<4;r++){
                int co = mw + i*16 + lq*4 + r;
                U[(size_t)co*S3 + opos] = acc[i][jj][r];
            }
        }
    }
}

// ---------------- 3x3x3 conv via MFMA: persistent B tile + reg-A 2-tap prefetch + lgkm barriers ----------------
// Per cb: stage [3z][6y][34x] x 32ci once (stride 40, 49KB), then 27 taps barrier-free.
// A-frags global->VGPR, rotating A0<-A1<-N0 (2-tap distance); barriers never drain vmcnt,
// so A prefetch survives across cb boundaries. 14 barriers total.
__global__ __launch_bounds__(256,2) void conv_mfma_kernel(const unsigned short* __restrict__ Xp,
        const unsigned short* __restrict__ Wt, const float* __restrict__ bg,
        float* __restrict__ Y){
    __shared__ unsigned short sB[612*40];   // 48,960 B
    const int nt = blockIdx.x;     // 0..255: z(32) x ygrp(8)
    const int mt = blockIdx.y;     // 0..1
    const int z  = nt >> 3;
    const int y0 = (nt & 7) * 4;
    const int t = threadIdx.x, w = t>>6, l = t&63;
    const int mw = (w & 1) * 64, nw = (w >> 1) * 64;
    const int lm = l & 15, lq = l >> 4;
    const unsigned short* ap = Wt + (size_t)(mt*128 + mw + lm)*32 + lq*8;

    floatx4 acc[4][4];
    #pragma unroll
    for (int i=0;i<4;i++)
        #pragma unroll
        for (int j=0;j<4;j++) acc[i][j] = (floatx4){0.f,0.f,0.f,0.f};

    // A prefetch pipeline, depth 2: linear u = cb*27 + tap, A step = tap*7 + cb
    short8 A0[4], A1[4];
    #pragma unroll
    for (int i=0;i<4;i++) A0[i] = *(const short8*)(ap + i*512);                    // u=0: step 0
    #pragma unroll
    for (int i=0;i<4;i++) A1[i] = *(const short8*)(ap + (size_t)7*8192 + i*512);   // u=1: tap1,cb0 -> step 7

    for (int cb = 0; cb < 7; ++cb){
        LGKM_BARRIER();   // all waves finished reading previous tile (ds ops only)
        for (int idx = t; idx < 2448; idx += 256){
            int p = idx >> 2, q = idx & 3;
            int zz = p / 204, rem = p % 204;
            int yy = rem / 34, x = rem - yy*34;
            uint4 v = *(const uint4*)&Xp[((size_t)((z+zz)*1156 + (y0+yy)*34 + x))*CPAD + cb*32 + q*8];
            *(uint4*)&sB[p*40 + q*8] = v;
        }
        LGKM_BARRIER();   // ds_writes visible to all waves
        #pragma unroll 1
        for (int tap = 0; tap < 27; ++tap){
            // prefetch A for u+2 (wave-uniform scalar offset)
            int u2 = cb*27 + tap + 2; if (u2 > 188) u2 = 188;
            int cb2 = u2 / 27, tap2 = u2 - cb2*27;
            const unsigned short* apn = ap + (size_t)(tap2*7 + cb2)*8192;
            short8 N0[4];
            #pragma unroll
            for (int i=0;i<4;i++) N0[i] = *(const short8*)(apn + i*512);
            const int dz = tap/9, r9 = tap - dz*9;
            const int dy = r9/3, dx = r9 - dy*3;
            short8 bf[4];
            #pragma unroll
            for (int j=0;j<4;j++){
                int n = nw + j*16 + lm;
                bf[j] = *(const short8*)&sB[(dz*204 + ((n>>5)+dy)*34 + (n&31)+dx)*40 + lq*8];
            }
            #pragma unroll
            for (int i=0;i<4;i++)
                #pragma unroll
                for (int j=0;j<4;j++)
                    acc[i][j] = __builtin_amdgcn_mfma_f32_16x16x32_bf16(A0[i], bf[j], acc[i][j], 0,0,0);
            #pragma unroll
            for (int i=0;i<4;i++){ A0[i] = A1[i]; A1[i] = N0[i]; }
        }
    }
    #pragma unroll
    for (int i=0;i<4;i++){
        #pragma unroll
        for (int j=0;j<4;j++){
            const int n = nw + j*16 + lm;
            const size_t pp = ((size_t)z<<10) + ((size_t)(y0 + (n>>5))<<5) + (n&31);
            #pragma unroll
            for (int r=0;r<4;r++){
                int gm = mt*128 + mw + i*16 + lq*4 + r;
                if (gm < CC) Y[(size_t)gm*S3 + pp] = acc[i][j][r] + bg[gm];
            }
        }
    }
}

// ---------------- final 219->3 conv: persistent spatial B tile, reg-A (27 frags), 14 barriers ----------------
__global__ __launch_bounds__(256,2) void convout_mfma_kernel(const unsigned short* __restrict__ Xp,
        const unsigned short* __restrict__ Wt2, const float* __restrict__ bgl,
        float* __restrict__ Y){
    __shared__ unsigned short sB[612*36];   // 44,064 B: [3z][6y][34x] x 32ci (stride 36)
    const int nt = blockIdx.x;      // z(32) x ygrp(8)
    const int z  = nt >> 3;
    const int y0 = (nt & 7) * 4;
    const int t = threadIdx.x, w = t>>6, l = t&63;
    const int nw = w * 32;
    const int lm = l & 15, lq = l >> 4;
    floatx4 acc[2];
    acc[0] = (floatx4){0.f,0.f,0.f,0.f};
    acc[1] = (floatx4){0.f,0.f,0.f,0.f};

    for (int cb = 0; cb < 7; ++cb){
        __syncthreads();
        for (int idx = t; idx < 2448; idx += 256){
            int p = idx >> 2, q = idx & 3;
            int zz = p / 204, rem = p % 204;
            int yy = rem / 34, x = rem - yy*34;
            uint4 v = *(const uint4*)&Xp[((size_t)((z+zz)*1156 + (y0+yy)*34 + x))*CPAD + cb*32 + q*8];
            *(uint4*)&sB[p*36 + q*8] = v;
        }
        short8 af[27];
        {
            const unsigned short* wp = Wt2 + ((size_t)(cb*16 + lm))*32 + lq*8;
            #pragma unroll
            for (int tap = 0; tap < 27; ++tap)
                af[tap] = *(const short8*)(wp + (size_t)tap*3584);   // 7*16*32 per tap
        }
        __syncthreads();
        #pragma unroll
        for (int tap = 0; tap < 27; ++tap){
            const int dz = tap/9, dy = (tap/3)%3, dx = tap%3;
            #pragma unroll
            for (int j=0;j<2;j++){
                int n = nw + j*16 + lm;
                int r = n >> 5, x = n & 31;
                short8 bf = *(const short8*)&sB[(dz*204 + (r+dy)*34 + (x+dx))*36 + lq*8];
                acc[j] = __builtin_amdgcn_mfma_f32_16x16x32_bf16(af[tap], bf, acc[j], 0,0,0);
            }
        }
    }
    if (lq == 0){
        #pragma unroll
        for (int j = 0; j < 2; j++){
            int n = nw + j*16 + lm;
            size_t pp = ((size_t)z<<10) + ((size_t)(y0 + (n>>5))<<5) + (n&31);
            #pragma unroll
            for (int r = 0; r < 3; r++)
                Y[(size_t)r*S3 + pp] = acc[j][r] + bgl[r];
        }
    }
}

extern "C" void kernel_launch(void* const* d_in, const int* in_sizes, int n_in,
                              void* d_out, int out_size, void* d_ws, size_t ws_size,
                              hipStream_t stream) {
    const float* src   = (const float*)d_in[0];
    const float* tgt   = (const float*)d_in[1];
    const float* Cmat  = (const float*)d_in[2];
    const float* up_w  = (const float*)d_in[3];
    const float* c1_w  = (const float*)d_in[5];
    const float* c1_b  = (const float*)d_in[6];
    const float* c2_w  = (const float*)d_in[7];
    const float* c2_b  = (const float*)d_in[8];
    const float* out_w = (const float*)d_in[9];
    const float* out_b = (const float*)d_in[10];

    float* out = (float*)d_out;                          // Cn [219*S3] then out [3*S3]
    char* ws = (char*)d_ws;
    unsigned short* Xp = (unsigned short*)ws;            // 34^3 x 224 bf16 = 17,608,192 B
    float*  U  = (float*)(ws + 17608192);                // 64*S3 fp32 = 8,388,608 B
    unsigned short* Wt = (unsigned short*)(ws + 17608192);       // aliases U (3,096,576 B)
    unsigned short* Cp = (unsigned short*)(ws + 25996800);       // 18^3 x 416 bf16 = 4,852,224 B
    unsigned short* Wu = (unsigned short*)(ws + 25996800 + 4852224); // 3,407,872 B
    float* srcp = (float*)(ws + 25996800);               // aliases Cp/Wu (10,061,824 B)
    unsigned short* Wt2 = (unsigned short*)(ws + 25996800); // aliases srcp after corr (193,536 B)
    float* stats = (float*)(ws + 36058624);              // 2 KB

    hipMemsetAsync(Xp, 0, 17608192, stream);             // halo + pad channels
    hipMemsetAsync(Cp, 0, 4852224, stream);

    // ---- upsample (411->64, k4 s2) as 8 parity GEMMs + instance-norm + leaky ----
    pack16_kernel<<<dim3(256,7), 256, 0, stream>>>(Cmat, Cp);
    wupack_kernel<<<6656, 256, 0, stream>>>(up_w, Wu);
    ups_mfma_kernel<<<512, 256, 0, stream>>>(Cp, Wu, U);
    stats_kernel<<<64, 256, 0, stream>>>(U, stats, 64);
    pack_kernel<<<dim3(1024,1), 256, 0, stream>>>(U, stats, stats+64, Xp, 64, 128, 1); // Cup -> ch 128..191
    // ---- concat: tgt -> ch 0..63, src -> ch 64..127 (raw) ----
    pack_kernel<<<dim3(1024,1), 256, 0, stream>>>(tgt, nullptr, nullptr, Xp, 64, 0, 0);
    pack_kernel<<<dim3(1024,1), 256, 0, stream>>>(src, nullptr, nullptr, Xp, 64, 64, 0);
    // ---- correlation volume -> ch 192..218 ----
    pad_kernel<<<9826, 256, 0, stream>>>(src, srcp);
    corr_kernel<<<128, 256, 0, stream>>>(tgt, srcp, Xp);
    // ---- out-conv weight pack (srcp region is free after corr) ----
    wpack_out_kernel<<<378, 256, 0, stream>>>(out_w, Wt2);
    // ---- conv1 (219->219) MFMA ----
    wpack_kernel<<<6048, 256, 0, stream>>>(c1_w, Wt, 1);
    conv_mfma_kernel<<<dim3(256,2), 256, 0, stream>>>(Xp, Wt, c1_b, out);
    stats_kernel<<<219, 256, 0, stream>>>(out, stats, 219);
    pack_kernel<<<dim3(1024,4), 256, 0, stream>>>(out, stats, stats+219, Xp, 219, 0, 1);
    // ---- conv2 (219->219) MFMA ----
    wpack_kernel<<<6048, 256, 0, stream>>>(c2_w, Wt, 0);
    conv_mfma_kernel<<<dim3(256,2), 256, 0, stream>>>(Xp, Wt, c2_b, out);
    // ---- norm + leaky: fp32 Cn to d_out, bf16 packed Cn to Xp ----
    stats_kernel<<<219, 256, 0, stream>>>(out, stats, 219);
    pack_kernel<<<dim3(1024,4), 256, 0, stream>>>(out, stats, stats+219, Xp, 219, 0, 1);
    norm_apply_kernel<<<(219*(S3/4))/256, 256, 0, stream>>>(out, stats, out, 219);
    // ---- final 219->3 conv via MFMA ----
    convout_mfma_kernel<<<256, 256, 0, stream>>>(Xp, Wt2, out_b, out + (size_t)CC*S3);
}